// Round 10
// baseline (833.056 us; speedup 1.0000x reference)
//
#include <hip/hip_runtime.h>
#include <hip/hip_bf16.h>
#include <stdint.h>

using short8 = __attribute__((ext_vector_type(8))) short;
using us4    = __attribute__((ext_vector_type(4))) unsigned short;
using f32x4  = __attribute__((ext_vector_type(4))) float;
using bf16   = __hip_bfloat16;

constexpr int CB=4, CS=512, CF=16, CD=512, CH=8, CL=6, CDFF=2048, CNC=12, CRPH=64, CDH=64;

__device__ inline void gload_lds16(const void* g, void* l) {
    __builtin_amdgcn_global_load_lds((const __attribute__((address_space(1))) void*)g,
                                     (__attribute__((address_space(3))) void*)l, 16, 0, 0);
}
__device__ inline float bfbits2f(unsigned short u) {
    return __uint_as_float(((uint32_t)u) << 16);
}
__device__ inline unsigned short f2bfbits(float f) {
    return __builtin_bit_cast(unsigned short, __float2bfloat16(f));
}

// ---------------------------------------------------------------------------
template<int BM, int BN, int TPB>
struct MMGeom {
    static constexpr int WC  = (TPB == 512) ? 4 : 2;
    static constexpr int WR  = (TPB/64)/WC;
    static constexpr int RS  = BM/WR;
    static constexpr int CSP = BN/WC;
    static constexpr int MR  = RS/16;
    static constexpr int NR  = CSP/16;
    static constexpr int NLD = (BM+BN)*128/(TPB*16);
};

// BK=64 tile staging: LDS rows 128 B, XOR-swizzled (slot ^= row&7), linear dest +
// inverse-swizzled global source (both-sides rule).
template<int BM, int BN, int TPB>
__device__ inline void stage_tile(const bf16* A, int lda, const bf16* W, int ldw, int k0,
                                  char* As, char* Bs) {
    constexpr int AC = (BM*128)/(TPB*16);
    constexpr int BC = (BN*128)/(TPB*16);
    const int tid = threadIdx.x;
#pragma unroll
    for (int i = 0; i < AC; i++) {
        int s = i*TPB + tid;
        int r = s >> 3, u = s & 7;
        const char* gp = (const char*)(A + (size_t)r*lda + k0) + ((u ^ (r&7))*16);
        gload_lds16(gp, As + (size_t)(s & ~63)*16);
    }
#pragma unroll
    for (int i = 0; i < BC; i++) {
        int s = i*TPB + tid;
        int r = s >> 3, u = s & 7;
        const char* gp = (const char*)(W + (size_t)r*ldw + k0) + ((u ^ (r&7))*16);
        gload_lds16(gp, Bs + (size_t)(s & ~63)*16);
    }
}

template<int BM, int BN, int TPB>
__device__ inline void compute_tile64(const char* As, const char* Bs,
                                      int wr, int wc, int c, int g,
                                      f32x4 (&acc)[MMGeom<BM,BN,TPB>::MR][MMGeom<BM,BN,TPB>::NR]) {
    using G = MMGeom<BM,BN,TPB>;
#pragma unroll
    for (int kk = 0; kk < 2; kk++) {
        short8 af[G::MR], bfv[G::NR];
#pragma unroll
        for (int m = 0; m < G::MR; m++) {
            int row = wr*G::RS + m*16 + c;
            af[m] = *(const short8*)(As + row*128 + (((kk*4+g) ^ (row&7))*16));
        }
#pragma unroll
        for (int n = 0; n < G::NR; n++) {
            int row = wc*G::CSP + n*16 + c;
            bfv[n] = *(const short8*)(Bs + row*128 + (((kk*4+g) ^ (row&7))*16));
        }
#pragma unroll
        for (int m = 0; m < G::MR; m++)
#pragma unroll
            for (int n = 0; n < G::NR; n++)
                acc[m][n] = __builtin_amdgcn_mfma_f32_16x16x32_bf16(af[m], bfv[n], acc[m][n], 0, 0, 0);
    }
}

// 4-buffer ring, ONE barrier per K-step (race-free: buffer t&3 rewritten by
// stage(t+4), issued after barrier(t+1) which all waves pass only after compute(t)).
template<int BM, int BN, int TPB>
__device__ inline void mm_core_pipe(const bf16* A, int lda, const bf16* W, int ldw, int K,
                                    char* smem,
                                    f32x4 (&acc)[MMGeom<BM,BN,TPB>::MR][MMGeom<BM,BN,TPB>::NR]) {
    using G = MMGeom<BM,BN,TPB>;
    constexpr int SSZ = (BM+BN)*128;
    const int tid = threadIdx.x;
    const int lane = tid & 63, wv = tid >> 6;
    const int wr = wv / G::WC, wc = wv % G::WC;
    const int g = lane >> 4, c = lane & 15;

    const int nk = K >> 6;
    stage_tile<BM,BN,TPB>(A, lda, W, ldw, 0, smem, smem + BM*128);
    if (nk > 1) stage_tile<BM,BN,TPB>(A, lda, W, ldw, 64, smem + SSZ, smem + SSZ + BM*128);

    for (int t = 0; t < nk; t++) {
        char* bc = smem + (size_t)(t & 3)*SSZ;
        if (t + 2 < nk) {
            char* bs = smem + (size_t)((t+2) & 3)*SSZ;
            stage_tile<BM,BN,TPB>(A, lda, W, ldw, (t+2)*64, bs, bs + BM*128);
            asm volatile("s_waitcnt vmcnt(%0)" :: "n"(2*G::NLD) : "memory");
        } else if (t + 1 < nk) {
            asm volatile("s_waitcnt vmcnt(%0)" :: "n"(G::NLD) : "memory");
        } else {
            asm volatile("s_waitcnt vmcnt(0)" ::: "memory");
        }
        __builtin_amdgcn_s_barrier();
        compute_tile64<BM,BN,TPB>(bc, bc + BM*128, wr, wc, c, g, acc);
    }
}

// Plain GEMM. EPI: 0 = bf16+bias ; 1 = bf16+bias+relu
template<int BM, int BN, int EPI, int TPB>
__global__ __launch_bounds__(TPB) void k_mm(const bf16* __restrict__ A, int lda,
                                            const bf16* __restrict__ W, int ldw,
                                            const float* __restrict__ bias,
                                            bf16* __restrict__ Cb, int ldc, int K) {
    using G = MMGeom<BM,BN,TPB>;
    __shared__ char smem[4*(BM+BN)*128];
    const int bm = blockIdx.y * BM, bn = blockIdx.x * BN;
    f32x4 acc[G::MR][G::NR] = {};
    mm_core_pipe<BM,BN,TPB>(A + (size_t)bm*lda, lda, W + (size_t)bn*ldw, ldw, K, smem, acc);
    const int lane = threadIdx.x & 63, wv = threadIdx.x >> 6;
    const int wr = wv / G::WC, wc = wv % G::WC;
    const int g = lane >> 4, c = lane & 15;
#pragma unroll
    for (int m = 0; m < G::MR; m++)
#pragma unroll
        for (int n = 0; n < G::NR; n++)
#pragma unroll
            for (int j = 0; j < 4; j++) {
                int row = bm + wr*G::RS + m*16 + g*4 + j;
                int col = bn + wc*G::CSP + n*16 + c;
                float v = acc[m][n][j] + bias[col];
                if (EPI == 1) v = fmaxf(v, 0.0f);
                Cb[(size_t)row*ldc + col] = __float2bfloat16(v);
            }
}

// ---------------------------------------------------------------------------
// Fused GEMM + bias + residual + LayerNorm via stripe-counter fixup.
// 64x64 tiles, grid (N/64=8, M/64=32). Each block writes x = acc+bias+h to tmp,
// accumulates per-row sum/sumsq (LDS -> global atomics), arrives on the stripe
// counter (agent release). 8th arriver (acquire) re-reads the stripe, applies
// LN -> h (f32) + hb (bf16), and resets counters/sums (self-cleaning).
__global__ __launch_bounds__(512) void k_mm_lnfix(const bf16* __restrict__ A, int lda,
                                                  const bf16* __restrict__ W, int ldw, int K,
                                                  const float* __restrict__ bias,
                                                  float* __restrict__ h, bf16* __restrict__ hb,
                                                  float* __restrict__ tmp,
                                                  const float* __restrict__ lns,
                                                  const float* __restrict__ lnb,
                                                  float* __restrict__ Ssum,
                                                  float* __restrict__ Qsum,
                                                  unsigned int* __restrict__ cnt) {
    constexpr int BM = 64, BN = 64, TPB = 512;
    using G = MMGeom<BM,BN,TPB>;   // WC=4 WR=2 RS=32 CSP=16 MR=2 NR=1 NLD=2
    __shared__ char smem[4*(BM+BN)*128];     // 64 KB ring
    __shared__ float lsS[BM], lsQ[BM];
    __shared__ unsigned int s_old;

    const int bm = blockIdx.y * BM, bn = blockIdx.x * BN;
    const int tid = threadIdx.x;
    const int lane = tid & 63, wv = tid >> 6;
    const int wr = wv / G::WC, wc = wv % G::WC;
    const int g = lane >> 4, c = lane & 15;

    f32x4 acc[G::MR][G::NR] = {};
    mm_core_pipe<BM,BN,TPB>(A + (size_t)bm*lda, lda, W + (size_t)bn*ldw, ldw, K, smem, acc);

    if (tid < BM) { lsS[tid] = 0.0f; lsQ[tid] = 0.0f; }
    __syncthreads();

    // x = acc + bias + resid; write tmp; per-row partials
    float s_[2][4], q_[2][4];
#pragma unroll
    for (int m = 0; m < 2; m++)
#pragma unroll
        for (int j = 0; j < 4; j++) {
            int rl = wr*32 + m*16 + g*4 + j;
            int col = bn + wc*16 + c;
            float x = acc[m][0][j] + bias[col] + h[(size_t)(bm+rl)*CD + col];
            tmp[(size_t)(bm+rl)*CD + col] = x;
            s_[m][j] = x; q_[m][j] = x*x;
        }
#pragma unroll
    for (int m = 0; m < 2; m++)
#pragma unroll
        for (int j = 0; j < 4; j++)
#pragma unroll
            for (int off = 1; off < 16; off <<= 1) {
                s_[m][j] += __shfl_xor(s_[m][j], off);
                q_[m][j] += __shfl_xor(q_[m][j], off);
            }
    if (c == 0) {
#pragma unroll
        for (int m = 0; m < 2; m++)
#pragma unroll
            for (int j = 0; j < 4; j++) {
                int rl = wr*32 + m*16 + g*4 + j;
                atomicAdd(&lsS[rl], s_[m][j]);
                atomicAdd(&lsQ[rl], q_[m][j]);
            }
    }
    __syncthreads();
    if (tid < BM) {
        atomicAdd(&Ssum[bm + tid], lsS[tid]);
        atomicAdd(&Qsum[bm + tid], lsQ[tid]);
    }
    __syncthreads();   // all tmp stores + atomics done (implicit vmcnt drain)
    if (tid == 0) {
        __builtin_amdgcn_fence(__ATOMIC_RELEASE, "agent");
        s_old = __hip_atomic_fetch_add(&cnt[blockIdx.y], 1u, __ATOMIC_ACQ_REL,
                                       __HIP_MEMORY_SCOPE_AGENT);
    }
    __syncthreads();
    if (s_old == 7) {
        __builtin_amdgcn_fence(__ATOMIC_ACQUIRE, "agent");
        int r = tid >> 3, cc0 = (tid & 7) * 64;
        int row = bm + r;
        float S = Ssum[row], Q = Qsum[row];
        float mean = S * (1.0f/CD);
        float var  = Q * (1.0f/CD) - mean*mean;
        float rstd = rsqrtf(var + 1e-5f);
        for (int c4 = 0; c4 < 64; c4 += 4) {
            int col = cc0 + c4;
            float4 x = *(const float4*)&tmp[(size_t)row*CD + col];
            float4 sc = *(const float4*)&lns[col];
            float4 bc = *(const float4*)&lnb[col];
            float4 y;
            y.x = (x.x-mean)*rstd*sc.x + bc.x;
            y.y = (x.y-mean)*rstd*sc.y + bc.y;
            y.z = (x.z-mean)*rstd*sc.z + bc.z;
            y.w = (x.w-mean)*rstd*sc.w + bc.w;
            *(float4*)&h[(size_t)row*CD + col] = y;
            us4 ob;
            ob[0] = f2bfbits(y.x); ob[1] = f2bfbits(y.y);
            ob[2] = f2bfbits(y.z); ob[3] = f2bfbits(y.w);
            *(us4*)(hb + (size_t)row*CD + col) = ob;
        }
        if ((tid & 7) == 0) { Ssum[row] = 0.0f; Qsum[row] = 0.0f; }
        if (tid == 0)
            __hip_atomic_store(&cnt[blockIdx.y], 0u, __ATOMIC_RELAXED, __HIP_MEMORY_SCOPE_AGENT);
    }
}

// qkv GEMM: writes Q,K into qkvb; V columns written transposed into vtb.
__global__ __launch_bounds__(512) void k_mm_qkv(const bf16* __restrict__ A,
                                                const bf16* __restrict__ W,
                                                const float* __restrict__ bias,
                                                bf16* __restrict__ qkvb,
                                                bf16* __restrict__ vtb) {
    constexpr int BM = 128, BN = 128, TPB = 512;
    using G = MMGeom<BM,BN,TPB>;
    __shared__ char smem[4*(BM+BN)*128];
    const int bm = blockIdx.y * BM, bn = blockIdx.x * BN;
    f32x4 acc[G::MR][G::NR] = {};
    mm_core_pipe<BM,BN,TPB>(A + (size_t)bm*CD, CD, W + (size_t)bn*CD, CD, CD, smem, acc);
    const int lane = threadIdx.x & 63, wv = threadIdx.x >> 6;
    const int wr = wv / G::WC, wc = wv % G::WC;
    const int g = lane >> 4, c = lane & 15;
    if (bn < 2*CD) {
#pragma unroll
        for (int m = 0; m < G::MR; m++)
#pragma unroll
            for (int n = 0; n < G::NR; n++)
#pragma unroll
                for (int j = 0; j < 4; j++) {
                    int row = bm + wr*G::RS + m*16 + g*4 + j;
                    int col = bn + wc*G::CSP + n*16 + c;
                    qkvb[(size_t)row*(3*CD) + col] = __float2bfloat16(acc[m][n][j] + bias[col]);
                }
    } else {
#pragma unroll
        for (int m = 0; m < G::MR; m++)
#pragma unroll
            for (int n = 0; n < G::NR; n++) {
                int row0 = bm + wr*G::RS + m*16 + g*4;
                int col  = bn + wc*G::CSP + n*16 + c;
                int z = (row0 >> 9)*8 + ((col - 2*CD) >> 6);
                int d = (col - 2*CD) & 63;
                int s0 = row0 & 511;
                float bcol = bias[col];
                us4 o;
#pragma unroll
                for (int j = 0; j < 4; j++) o[j] = f2bfbits(acc[m][n][j] + bcol);
                *(us4*)(vtb + ((size_t)z*CDH + d)*CS + s0) = o;
            }
    }
}

// ---------------------------------------------------------------------------
// Fused attention: 4 distinct K/V buffers, ONE barrier per KV tile, defer-max.
__global__ __launch_bounds__(256) void k_attn_fused(const bf16* __restrict__ qkv,
                                                    const bf16* __restrict__ vt,
                                                    const bf16* __restrict__ bias,
                                                    bf16* __restrict__ att) {
    __shared__ char Ksm[4][16384];
    __shared__ char Vsm[4][16384];
    __shared__ char Ps[16384];

    const int z = blockIdx.y, b = z >> 3, h = z & 7;
    const int qbase = blockIdx.x * 64;
    const int tid = threadIdx.x, l = tid & 63, w = tid >> 6;
    const int g = l >> 4, c = l & 15, swz = l & 7;
    const int q_global = qbase + w*16 + c;

    const bf16* qrow = qkv + ((size_t)(b*CS + q_global))*(3*CD) + h*CDH;
    short8 bq0 = *(const short8*)(qrow + g*8);
    short8 bq1 = *(const short8*)(qrow + 32 + g*8);
    const bf16* brow = bias + ((size_t)z*CS + q_global)*CS;

    float mrun = -1e30f, lsum = 0.0f;
    f32x4 accO[4] = {};
    char* Pb = Ps + w*4096;

    auto stageKV = [&](int kv0, char* Ks, char* Vs) {
#pragma unroll
        for (int i = 0; i < 4; i++) {
            int s = i*256 + tid;
            int r = s >> 3, u = s & 7;
            const bf16* gk = qkv + ((size_t)(b*CS + kv0 + r))*(3*CD) + CD + h*CDH + ((u ^ (r&7)) * 8);
            gload_lds16(gk, Ks + (size_t)(s & ~63)*16);
        }
#pragma unroll
        for (int i = 0; i < 4; i++) {
            int s = i*256 + tid;
            int d = s >> 4, u = s & 15;
            const bf16* gv = vt + ((size_t)(z*CDH + d))*CS + kv0 + ((u ^ (d&7)) * 8);
            gload_lds16(gv, Vs + (size_t)(s & ~63)*16);
        }
    };

    stageKV(0,   Ksm[0], Vsm[0]);
    stageKV(128, Ksm[1], Vsm[1]);

    for (int t = 0; t < 4; t++) {
        int kv0 = t * 128;
        if (t < 2) stageKV((t+2)*128, Ksm[t+2], Vsm[t+2]);
        if (t == 0)      asm volatile("s_waitcnt vmcnt(32)" ::: "memory");
        else if (t == 1) asm volatile("s_waitcnt vmcnt(40)" ::: "memory");
        else if (t == 2) asm volatile("s_waitcnt vmcnt(32)" ::: "memory");
        else             asm volatile("s_waitcnt vmcnt(0)" ::: "memory");
        __builtin_amdgcn_s_barrier();
        const char* Kc = Ksm[t];
        const char* Vc = Vsm[t];

        float sv[8][4];
        float tmax = -1e30f;
#pragma unroll
        for (int n = 0; n < 8; n++) {
            int row = n*16 + c;
            short8 af0 = *(const short8*)(Kc + row*128 + ((g    ^ swz) * 16));
            short8 af1 = *(const short8*)(Kc + row*128 + (((4+g) ^ swz) * 16));
            f32x4 a = {};
            a = __builtin_amdgcn_mfma_f32_16x16x32_bf16(af0, bq0, a, 0, 0, 0);
            a = __builtin_amdgcn_mfma_f32_16x16x32_bf16(af1, bq1, a, 0, 0, 0);
            us4 b4 = *(const us4*)(brow + kv0 + n*16 + g*4);
#pragma unroll
            for (int j = 0; j < 4; j++) {
                sv[n][j] = a[j] * 0.125f + bfbits2f(b4[j]);
                tmax = fmaxf(tmax, sv[n][j]);
            }
        }
        tmax = fmaxf(tmax, __shfl_xor(tmax, 16));
        tmax = fmaxf(tmax, __shfl_xor(tmax, 32));
        if (!__all(tmax - mrun <= 8.0f)) {
            float mnew = fmaxf(mrun, tmax);
            float corr = __expf(mrun - mnew);
            lsum *= corr;
#pragma unroll
            for (int n2 = 0; n2 < 4; n2++)
#pragma unroll
                for (int j = 0; j < 4; j++) accO[n2][j] *= corr;
            mrun = mnew;
        }
        float tsum = 0.0f;
#pragma unroll
        for (int n = 0; n < 8; n++)
#pragma unroll
            for (int j = 0; j < 4; j++) {
                float e = __expf(sv[n][j] - mrun);
                sv[n][j] = e;
                tsum += e;
            }
        tsum += __shfl_xor(tsum, 16);
        tsum += __shfl_xor(tsum, 32);
        lsum += tsum;

#pragma unroll
        for (int n = 0; n < 8; n++) {
            us4 pk;
#pragma unroll
            for (int j = 0; j < 4; j++) pk[j] = f2bfbits(sv[n][j]);
            *(us4*)(Pb + c*256 + ((n*32 + g*8) ^ (swz << 4))) = pk;
        }

#pragma unroll
        for (int n2 = 0; n2 < 4; n2++) {
            int d = n2*16 + c;
#pragma unroll
            for (int kk = 0; kk < 4; kk++) {
                short8 av = *(const short8*)(Vc + d*256 + (((kk*4 + g) ^ swz) * 16));
                short8 bp = *(const short8*)(Pb + c*256 + (((kk*64 + g*16) ^ (swz << 4))));
                accO[n2] = __builtin_amdgcn_mfma_f32_16x16x32_bf16(av, bp, accO[n2], 0, 0, 0);
            }
        }
    }

    float inv = 1.0f / lsum;
    bf16* orow = att + ((size_t)(b*CS + q_global))*CD + h*CDH;
#pragma unroll
    for (int n2 = 0; n2 < 4; n2++) {
        us4 o;
#pragma unroll
        for (int j = 0; j < 4; j++) o[j] = f2bfbits(accO[n2][j] * inv);
        *(us4*)(orow + n2*16 + g*4) = o;
    }
}

// ---------------------------------------------------------------------------
__global__ void k_standardize(const float* __restrict__ x, float* __restrict__ ts,
                              float* __restrict__ fs) {
    int b = blockIdx.x, ch = blockIdx.y, tid = threadIdx.x;
    __shared__ float red[256];
    float v0 = x[(b*CS + tid)*CF + ch];
    float v1 = x[(b*CS + tid + 256)*CF + ch];
    red[tid] = v0 + v1; __syncthreads();
    for (int w = 128; w > 0; w >>= 1) { if (tid < w) red[tid] += red[tid+w]; __syncthreads(); }
    float mean = red[0] * (1.0f/CS); __syncthreads();
    float d0 = v0-mean, d1 = v1-mean;
    red[tid] = d0*d0 + d1*d1; __syncthreads();
    for (int w = 128; w > 0; w >>= 1) { if (tid < w) red[tid] += red[tid+w]; __syncthreads(); }
    float inv = rsqrtf(red[0]*(1.0f/CS) + 1e-6f);
    float* o = ch == 0 ? ts : fs;
    o[b*CS + tid] = d0*inv; o[b*CS + tid + 256] = d1*inv;
}

__global__ __launch_bounds__(256) void k_relpos(const float* __restrict__ ts, const float* __restrict__ fs,
                         const float* __restrict__ w1, const float* __restrict__ b1,
                         const float* __restrict__ w2, const float* __restrict__ b2,
                         bf16* __restrict__ bias) {
    int idx = blockIdx.x * 256 + threadIdx.x;
    int j = idx & (CS-1), i = (idx >> 9) & (CS-1), b = idx >> 18;
    float dt = ts[b*CS + i] - ts[b*CS + j];
    float df = fs[b*CS + i] - fs[b*CS + j];
    float acc[CH];
#pragma unroll
    for (int h = 0; h < CH; h++) acc[h] = b2[h];
    for (int r = 0; r < CRPH; r++) {
        float hd = fmaxf(w1[r*2]*dt + w1[r*2+1]*df + b1[r], 0.0f);
#pragma unroll
        for (int h = 0; h < CH; h++) acc[h] += w2[h*CRPH + r] * hd;
    }
#pragma unroll
    for (int h = 0; h < CH; h++) {
        float v = fminf(fmaxf(acc[h], -5.0f), 5.0f);
        bias[((size_t)(b*CH + h)*CS + i)*CS + j] = __float2bfloat16(v);
    }
}

__global__ __launch_bounds__(256) void k_embed(const float* __restrict__ x, const float* __restrict__ w,
                        const float* __restrict__ bv, float* __restrict__ h, bf16* __restrict__ hb) {
    int idx = blockIdx.x * 256 + threadIdx.x;
    int d = idx & (CD-1), m = idx >> 9;
    const float* xr = x + m*CF;
    const float* wr = w + d*CF;
    float acc = bv[d];
#pragma unroll
    for (int f = 0; f < CF; f++) acc += xr[f]*wr[f];
    h[idx] = acc; hb[idx] = __float2bfloat16(acc);
}

// one-shot conversion of all 6 layers' weights
__global__ __launch_bounds__(256) void k_wconv_all(const float* __restrict__ aiw, const float* __restrict__ aow,
                        const float* __restrict__ f1w, const float* __restrict__ f2w,
                        bf16* __restrict__ dst) {
    int lyr = blockIdx.y;
    size_t i = ((size_t)blockIdx.x * 256 + threadIdx.x) * 8;
    const float* src; size_t off;
    if (i < 786432)       { src = aiw + (size_t)lyr* 786432; off = i; }
    else if (i < 1048576) { src = aow + (size_t)lyr* 262144; off = i - 786432; }
    else if (i < 2097152) { src = f1w + (size_t)lyr*1048576; off = i - 1048576; }
    else                  { src = f2w + (size_t)lyr*1048576; off = i - 2097152; }
    short8 o;
#pragma unroll
    for (int j = 0; j < 8; j++) o[j] = __builtin_bit_cast(short, __float2bfloat16(src[off + j]));
    *(short8*)(void*)(dst + (size_t)lyr*3145728 + i) = o;
}

// per-layer fallback weight conversion
__global__ __launch_bounds__(256) void k_wconv(const float* __restrict__ a0, const float* __restrict__ a1,
                        const float* __restrict__ a2, const float* __restrict__ a3,
                        bf16* __restrict__ dst) {
    size_t i = ((size_t)blockIdx.x * 256 + threadIdx.x) * 8;
    const float* src; size_t off;
    if (i < 786432)       { src = a0; off = i; }
    else if (i < 1048576) { src = a1; off = i - 786432; }
    else if (i < 2097152) { src = a2; off = i - 1048576; }
    else                  { src = a3; off = i - 2097152; }
    short8 o;
#pragma unroll
    for (int j = 0; j < 8; j++) o[j] = __builtin_bit_cast(short, __float2bfloat16(src[off + j]));
    *(short8*)(void*)(dst + i) = o;
}

__global__ __launch_bounds__(256) void k_pool(const float* __restrict__ h, float* __restrict__ rep) {
    int b = blockIdx.x, d0 = blockIdx.y * 64;
    int t = threadIdx.x, dl = t & 63, sg = t >> 6;
    float acc = 0.0f;
    for (int s = sg*128; s < sg*128 + 128; s++)
        acc += h[((size_t)(b*CS + s))*CD + d0 + dl];
    __shared__ float red[256];
    red[t] = acc; __syncthreads();
    if (t < 64)
        rep[b*CD + d0 + dl] = (red[t] + red[t+64] + red[t+128] + red[t+192]) * (1.0f/CS);
}

__global__ void k_fc(const float* __restrict__ rep, const float* __restrict__ fcw,
                     const float* __restrict__ fcb, float* __restrict__ out) {
    int b = blockIdx.x, cc = blockIdx.y, l = threadIdx.x;
    float acc = 0.0f;
    for (int d = l; d < CD; d += 64) acc += rep[b*CD + d] * fcw[cc*CD + d];
    for (int o = 32; o > 0; o >>= 1) acc += __shfl_xor(acc, o);
    if (l == 0) out[b*CNC + cc] = acc + fcb[cc];
}

// ---------------------------------------------------------------------------
extern "C" void kernel_launch(void* const* d_in, const int* in_sizes, int n_in,
                              void* d_out, int out_size, void* d_ws, size_t ws_size,
                              hipStream_t stream) {
    const float* x   = (const float*)d_in[0];
    const float* rw1 = (const float*)d_in[1];
    const float* rb1 = (const float*)d_in[2];
    const float* rw2 = (const float*)d_in[3];
    const float* rb2 = (const float*)d_in[4];
    const float* emw = (const float*)d_in[5];
    const float* emb = (const float*)d_in[6];
    const float* aiw = (const float*)d_in[7];
    const float* aib = (const float*)d_in[8];
    const float* aow = (const float*)d_in[9];
    const float* aob = (const float*)d_in[10];
    const float* f1w = (const float*)d_in[11];
    const float* f1b = (const float*)d_in[12];
    const float* f2w = (const float*)d_in[13];
    const float* f2b = (const float*)d_in[14];
    const float* l1s = (const float*)d_in[15];
    const float* l1b = (const float*)d_in[16];
    const float* l2s = (const float*)d_in[17];
    const float* l2b = (const float*)d_in[18];
    const float* fcw = (const float*)d_in[19];
    const float* fcb = (const float*)d_in[20];
    float* out = (float*)d_out;

    char* p = (char*)d_ws;
    auto alloc = [&](size_t bytes) { char* r = p; p += (bytes + 255) & ~(size_t)255; return r; };
    bf16*  biasb = (bf16*)alloc((size_t)CB*CH*CS*CS*2);    // 16.78 MB
    float* h     = (float*)alloc((size_t)CB*CS*CD*4);      // 4.19 MB
    bf16*  hb    = (bf16*)alloc((size_t)CB*CS*CD*2);       // 2.10 MB
    bf16*  qkvb  = (bf16*)alloc((size_t)CB*CS*3*CD*2);     // 6.29 MB
    bf16*  vtb   = (bf16*)alloc((size_t)CB*CH*CDH*CS*2);   // 2.10 MB
    bf16*  attb  = (bf16*)alloc((size_t)CB*CS*CD*2);       // 2.10 MB
    float* tmp   = (float*)alloc((size_t)CB*CS*CD*4);      // 4.19 MB
    bf16*  ffb   = (bf16*)alloc((size_t)CB*CS*CDFF*2);     // 8.39 MB
    bf16*  wl    = (bf16*)alloc((size_t)3145728*2);        // 6.29 MB (fallback)
    float* rep   = (float*)alloc((size_t)CB*CD*4);
    float* ts    = (float*)alloc(CB*CS*4);
    float* fs    = (float*)alloc(CB*CS*4);
    // sync buffers for LN fixup
    float* Ssum  = (float*)alloc((size_t)CB*CS*4);         // 2048 f32
    float* Qsum  = (float*)alloc((size_t)CB*CS*4);
    unsigned int* cnt = (unsigned int*)alloc(32*4);
    char* syncbase = (char*)Ssum;
    size_t syncbytes = (size_t)((char*)p - syncbase);

    size_t used = (size_t)(p - (char*)d_ws);
    const size_t WLE = 3145728;
    bool oneshot = (ws_size > used) && ((ws_size - used) >= (size_t)CL*WLE*2 + 256);
    bf16* wlall = (bf16*)alloc(oneshot ? (size_t)CL*WLE*2 : 0);

    const int M = CB*CS;  // 2048

    hipMemsetAsync(syncbase, 0, syncbytes, stream);
    k_standardize<<<dim3(CB,2), 256, 0, stream>>>(x, ts, fs);
    k_relpos<<<(CB*CS*CS)/256, 256, 0, stream>>>(ts, fs, rw1, rb1, rw2, rb2, biasb);
    k_embed<<<(M*CD)/256, 256, 0, stream>>>(x, emw, emb, h, hb);
    if (oneshot)
        k_wconv_all<<<dim3(1536, CL), 256, 0, stream>>>(aiw, aow, f1w, f2w, wlall);

    for (int l = 0; l < CL; l++) {
        const bf16* wbase = oneshot ? (wlall + (size_t)l*WLE) : wl;
        if (!oneshot)
            k_wconv<<<1536, 256, 0, stream>>>(aiw + (size_t)l*786432, aow + (size_t)l*262144,
                                              f1w + (size_t)l*1048576, f2w + (size_t)l*1048576, wl);
        const bf16* wl_aiw = wbase;
        const bf16* wl_aow = wbase + 786432;
        const bf16* wl_f1w = wbase + 1048576;
        const bf16* wl_f2w = wbase + 2097152;
        // qkv = h @ aiw^T + aib ; V part written transposed into vtb
        k_mm_qkv<<<dim3(12,16), 512, 0, stream>>>(hb, wl_aiw, aib + (size_t)l*3*CD, qkvb, vtb);
        // fused attention
        k_attn_fused<<<dim3(CS/64, CB*CH), 256, 0, stream>>>(qkvb, vtb, biasb, attb);
        // out projection + residual + LN1 (fused fixup)
        k_mm_lnfix<<<dim3(8,32), 512, 0, stream>>>(attb, CD, wl_aow, CD, CD,
                                                   aob + (size_t)l*CD, h, hb, tmp,
                                                   l1s + (size_t)l*CD, l1b + (size_t)l*CD,
                                                   Ssum, Qsum, cnt);
        // ff1 (relu)
        k_mm<128,128,1,512><<<dim3(16,16), 512, 0, stream>>>(hb, CD, wl_f1w, CD,
                                                             f1b + (size_t)l*CDFF, ffb, CDFF, CD);
        // ff2 + residual + LN2 (fused fixup)
        k_mm_lnfix<<<dim3(8,32), 512, 0, stream>>>(ffb, CDFF, wl_f2w, CDFF, CDFF,
                                                   f2b + (size_t)l*CD, h, hb, tmp,
                                                   l2s + (size_t)l*CD, l2b + (size_t)l*CD,
                                                   Ssum, Qsum, cnt);
    }

    k_pool<<<dim3(CB, CD/64), 256, 0, stream>>>(h, rep);
    k_fc<<<dim3(CB, CNC), 64, 0, stream>>>(rep, fcw, fcb, out);
}

// Round 11
// 540.026 us; speedup vs baseline: 1.5426x; 1.5426x over previous
//
#include <hip/hip_runtime.h>
#include <hip/hip_bf16.h>
#include <stdint.h>

using short8 = __attribute__((ext_vector_type(8))) short;
using us4    = __attribute__((ext_vector_type(4))) unsigned short;
using f32x4  = __attribute__((ext_vector_type(4))) float;
using bf16   = __hip_bfloat16;

constexpr int CB=4, CS=512, CF=16, CD=512, CH=8, CL=6, CDFF=2048, CNC=12, CRPH=64, CDH=64;
constexpr int MROWS = CB*CS;   // 2048

__device__ inline void gload_lds16(const void* g, void* l) {
    __builtin_amdgcn_global_load_lds((const __attribute__((address_space(1))) void*)g,
                                     (__attribute__((address_space(3))) void*)l, 16, 0, 0);
}
__device__ inline float bfbits2f(unsigned short u) {
    return __uint_as_float(((uint32_t)u) << 16);
}
__device__ inline unsigned short f2bfbits(float f) {
    return __builtin_bit_cast(unsigned short, __float2bfloat16(f));
}

// ---------------------------------------------------------------------------
template<int BM, int BN, int TPB>
struct MMGeom {
    static constexpr int WC  = (TPB == 512) ? 4 : 2;
    static constexpr int WR  = (TPB/64)/WC;
    static constexpr int RS  = BM/WR;
    static constexpr int CSP = BN/WC;
    static constexpr int MR  = RS/16;
    static constexpr int NR  = CSP/16;
    static constexpr int NLD = (BM+BN)*128/(TPB*16);
};

// BK=64 staging: LDS rows 128 B, XOR swizzle (slot ^= row&7); linear LDS dest +
// inverse-swizzled global source (both-sides rule).
template<int BM, int BN, int TPB>
__device__ inline void stage_tile(const bf16* A, int lda, const bf16* W, int ldw, int k0,
                                  char* As, char* Bs) {
    constexpr int AC = (BM*128)/(TPB*16);
    constexpr int BC = (BN*128)/(TPB*16);
    const int tid = threadIdx.x;
#pragma unroll
    for (int i = 0; i < AC; i++) {
        int s = i*TPB + tid;
        int r = s >> 3, u = s & 7;
        const char* gp = (const char*)(A + (size_t)r*lda + k0) + ((u ^ (r&7))*16);
        gload_lds16(gp, As + (size_t)(s & ~63)*16);
    }
#pragma unroll
    for (int i = 0; i < BC; i++) {
        int s = i*TPB + tid;
        int r = s >> 3, u = s & 7;
        const char* gp = (const char*)(W + (size_t)r*ldw + k0) + ((u ^ (r&7))*16);
        gload_lds16(gp, Bs + (size_t)(s & ~63)*16);
    }
}

// W-only staging for the LN-staged GEMMs (BN=128, TPB=512 -> 2 issues/thread)
__device__ inline void stageW128(const bf16* W, int ldw, int k0, char* Bs) {
    const int tid = threadIdx.x;
#pragma unroll
    for (int i = 0; i < 2; i++) {
        int s = i*512 + tid;
        int r = s >> 3, u = s & 7;
        const char* gp = (const char*)(W + (size_t)r*ldw + k0) + ((u ^ (r&7))*16);
        gload_lds16(gp, Bs + (size_t)(s & ~63)*16);
    }
}

template<int BM, int BN, int TPB>
__device__ inline void compute_tile64(const char* As, const char* Bs,
                                      int wr, int wc, int c, int g,
                                      f32x4 (&acc)[MMGeom<BM,BN,TPB>::MR][MMGeom<BM,BN,TPB>::NR]) {
    using G = MMGeom<BM,BN,TPB>;
#pragma unroll
    for (int kk = 0; kk < 2; kk++) {
        short8 af[G::MR], bfv[G::NR];
#pragma unroll
        for (int m = 0; m < G::MR; m++) {
            int row = wr*G::RS + m*16 + c;
            af[m] = *(const short8*)(As + row*128 + (((kk*4+g) ^ (row&7))*16));
        }
#pragma unroll
        for (int n = 0; n < G::NR; n++) {
            int row = wc*G::CSP + n*16 + c;
            bfv[n] = *(const short8*)(Bs + row*128 + (((kk*4+g) ^ (row&7))*16));
        }
#pragma unroll
        for (int m = 0; m < G::MR; m++)
#pragma unroll
            for (int n = 0; n < G::NR; n++)
                acc[m][n] = __builtin_amdgcn_mfma_f32_16x16x32_bf16(af[m], bfv[n], acc[m][n], 0, 0, 0);
    }
}

// 4-buffer ring, one barrier per K-step (proven race-free, r9).
template<int BM, int BN, int TPB>
__device__ inline void mm_core_pipe(const bf16* A, int lda, const bf16* W, int ldw, int K,
                                    char* smem,
                                    f32x4 (&acc)[MMGeom<BM,BN,TPB>::MR][MMGeom<BM,BN,TPB>::NR]) {
    using G = MMGeom<BM,BN,TPB>;
    constexpr int SSZ = (BM+BN)*128;
    const int tid = threadIdx.x;
    const int lane = tid & 63, wv = tid >> 6;
    const int wr = wv / G::WC, wc = wv % G::WC;
    const int g = lane >> 4, c = lane & 15;

    const int nk = K >> 6;
    stage_tile<BM,BN,TPB>(A, lda, W, ldw, 0, smem, smem + BM*128);
    if (nk > 1) stage_tile<BM,BN,TPB>(A, lda, W, ldw, 64, smem + SSZ, smem + SSZ + BM*128);

    for (int t = 0; t < nk; t++) {
        char* bc = smem + (size_t)(t & 3)*SSZ;
        if (t + 2 < nk) {
            char* bs = smem + (size_t)((t+2) & 3)*SSZ;
            stage_tile<BM,BN,TPB>(A, lda, W, ldw, (t+2)*64, bs, bs + BM*128);
            asm volatile("s_waitcnt vmcnt(%0)" :: "n"(2*G::NLD) : "memory");
        } else if (t + 1 < nk) {
            asm volatile("s_waitcnt vmcnt(%0)" :: "n"(G::NLD) : "memory");
        } else {
            asm volatile("s_waitcnt vmcnt(0)" ::: "memory");
        }
        __builtin_amdgcn_s_barrier();
        compute_tile64<BM,BN,TPB>(bc, bc + BM*128, wr, wc, c, g, acc);
    }
}

// ---------------------------------------------------------------------------
// LN-staged A GEMM pipe (BM=BN=128, TPB=512, K=512): A[r][k] is computed on the
// fly as LN-elem of tmpIn using the 8 per-colblock partial sums, converted to
// bf16 and ds_written to the swizzled LDS layout. W staged async (gload_lds).
__device__ inline void mm_lnA_pipe(const float* __restrict__ tmpIn,
                                   const float* __restrict__ Sp, const float* __restrict__ Qp,
                                   const float* __restrict__ lns, const float* __restrict__ lnb,
                                   int bm, const bf16* __restrict__ W, int ldw,
                                   char* smem, f32x4 (&acc)[4][2]) {
    const int tid = threadIdx.x;
    const int lane = tid & 63, wv = tid >> 6;
    const int wr = wv >> 2, wc = wv & 3;
    const int g = lane >> 4, c = lane & 15;
    char* A0 = smem;            char* B0 = smem + 128*128;
    char* A1 = smem + 256*128;  char* B1 = A1 + 128*128;

    const int r0 = tid >> 3, r1 = r0 + 64, u = tid & 7;
    float S0=0,Q0=0,S1=0,Q1=0;
#pragma unroll
    for (int j = 0; j < 8; j++) {
        S0 += Sp[j*MROWS + bm + r0]; Q0 += Qp[j*MROWS + bm + r0];
        S1 += Sp[j*MROWS + bm + r1]; Q1 += Qp[j*MROWS + bm + r1];
    }
    const float mean0 = S0*(1.0f/CD), mean1 = S1*(1.0f/CD);
    const float rstd0 = rsqrtf(Q0*(1.0f/CD) - mean0*mean0 + 1e-5f);
    const float rstd1 = rsqrtf(Q1*(1.0f/CD) - mean1*mean1 + 1e-5f);

    const float* p0 = tmpIn + (size_t)(bm + r0)*CD + u*8;
    const float* p1 = tmpIn + (size_t)(bm + r1)*CD + u*8;

    float4 x00,x01,x10,x11,sc0,sc1,bc0,bc1;
    auto loadA = [&](int k0) {
        x00 = *(const float4*)(p0 + k0);        x01 = *(const float4*)(p0 + k0 + 4);
        x10 = *(const float4*)(p1 + k0);        x11 = *(const float4*)(p1 + k0 + 4);
        sc0 = *(const float4*)(lns + k0 + u*8); sc1 = *(const float4*)(lns + k0 + u*8 + 4);
        bc0 = *(const float4*)(lnb + k0 + u*8); bc1 = *(const float4*)(lnb + k0 + u*8 + 4);
    };
    auto pk8 = [&](float4 a, float4 b2, float mean, float rstd,
                   float4 sa, float4 sb, float4 ba, float4 bb) -> short8 {
        short8 o;
        o[0]=(short)f2bfbits((a.x -mean)*rstd*sa.x+ba.x);
        o[1]=(short)f2bfbits((a.y -mean)*rstd*sa.y+ba.y);
        o[2]=(short)f2bfbits((a.z -mean)*rstd*sa.z+ba.z);
        o[3]=(short)f2bfbits((a.w -mean)*rstd*sa.w+ba.w);
        o[4]=(short)f2bfbits((b2.x-mean)*rstd*sb.x+bb.x);
        o[5]=(short)f2bfbits((b2.y-mean)*rstd*sb.y+bb.y);
        o[6]=(short)f2bfbits((b2.z-mean)*rstd*sb.z+bb.z);
        o[7]=(short)f2bfbits((b2.w-mean)*rstd*sb.w+bb.w);
        return o;
    };
    auto writeA = [&](char* As) {
        *(short8*)(As + r0*128 + ((u ^ (r0&7))*16)) = pk8(x00,x01,mean0,rstd0,sc0,sc1,bc0,bc1);
        *(short8*)(As + r1*128 + ((u ^ (r1&7))*16)) = pk8(x10,x11,mean1,rstd1,sc0,sc1,bc0,bc1);
    };

    stageW128(W, ldw, 0, B0);
    loadA(0);
    writeA(A0);
    __syncthreads();
    for (int t = 0; t < 8; t++) {
        char* Ac = (t&1)?A1:A0; char* Bc=(t&1)?B1:B0;
        char* An = (t&1)?A0:A1; char* Bn=(t&1)?B0:B1;
        if (t < 7) { stageW128(W, ldw, (t+1)*64, Bn); loadA((t+1)*64); }
        compute_tile64<128,128,512>(Ac, Bc, wr, wc, c, g, acc);
        if (t < 7) writeA(An);
        __syncthreads();
    }
}

// ---------------------------------------------------------------------------
// qkv GEMM, plain bf16 A (layer 0): Q,K -> qkvb; V -> vtb transposed.
__global__ __launch_bounds__(512) void k_mm_qkv(const bf16* __restrict__ A,
                                                const bf16* __restrict__ W,
                                                const float* __restrict__ bias,
                                                bf16* __restrict__ qkvb,
                                                bf16* __restrict__ vtb) {
    constexpr int BM = 128, BN = 128, TPB = 512;
    using G = MMGeom<BM,BN,TPB>;
    __shared__ char smem[4*(BM+BN)*128];
    const int bm = blockIdx.y * BM, bn = blockIdx.x * BN;
    f32x4 acc[G::MR][G::NR] = {};
    mm_core_pipe<BM,BN,TPB>(A + (size_t)bm*CD, CD, W + (size_t)bn*CD, CD, CD, smem, acc);
    const int lane = threadIdx.x & 63, wv = threadIdx.x >> 6;
    const int wr = wv / G::WC, wc = wv % G::WC;
    const int g = lane >> 4, c = lane & 15;
    if (bn < 2*CD) {
#pragma unroll
        for (int m = 0; m < G::MR; m++)
#pragma unroll
            for (int n = 0; n < G::NR; n++)
#pragma unroll
                for (int j = 0; j < 4; j++) {
                    int row = bm + wr*G::RS + m*16 + g*4 + j;
                    int col = bn + wc*G::CSP + n*16 + c;
                    qkvb[(size_t)row*(3*CD) + col] = __float2bfloat16(acc[m][n][j] + bias[col]);
                }
    } else {
#pragma unroll
        for (int m = 0; m < G::MR; m++)
#pragma unroll
            for (int n = 0; n < G::NR; n++) {
                int row0 = bm + wr*G::RS + m*16 + g*4;
                int col  = bn + wc*G::CSP + n*16 + c;
                int z = (row0 >> 9)*8 + ((col - 2*CD) >> 6);
                int d = (col - 2*CD) & 63;
                int s0 = row0 & 511;
                float bcol = bias[col];
                us4 o;
#pragma unroll
                for (int j = 0; j < 4; j++) o[j] = f2bfbits(acc[m][n][j] + bcol);
                *(us4*)(vtb + ((size_t)z*CDH + d)*CS + s0) = o;
            }
    }
}

// qkv GEMM with LN-staged A (layers 1..5).
__global__ __launch_bounds__(512) void k_mm_qkv_ln(const float* __restrict__ tmpIn,
                                                   const float* __restrict__ Sp,
                                                   const float* __restrict__ Qp,
                                                   const float* __restrict__ lns,
                                                   const float* __restrict__ lnb,
                                                   const bf16* __restrict__ W,
                                                   const float* __restrict__ bias,
                                                   bf16* __restrict__ qkvb,
                                                   bf16* __restrict__ vtb) {
    using G = MMGeom<128,128,512>;
    __shared__ char smem[2*256*128];
    const int bm = blockIdx.y * 128, bn = blockIdx.x * 128;
    f32x4 acc[4][2] = {};
    mm_lnA_pipe(tmpIn, Sp, Qp, lns, lnb, bm, W + (size_t)bn*CD, CD, smem, acc);
    const int lane = threadIdx.x & 63, wv = threadIdx.x >> 6;
    const int wr = wv >> 2, wc = wv & 3;
    const int g = lane >> 4, c = lane & 15;
    if (bn < 2*CD) {
#pragma unroll
        for (int m = 0; m < 4; m++)
#pragma unroll
            for (int n = 0; n < 2; n++)
#pragma unroll
                for (int j = 0; j < 4; j++) {
                    int row = bm + wr*64 + m*16 + g*4 + j;
                    int col = bn + wc*32 + n*16 + c;
                    qkvb[(size_t)row*(3*CD) + col] = __float2bfloat16(acc[m][n][j] + bias[col]);
                }
    } else {
#pragma unroll
        for (int m = 0; m < 4; m++)
#pragma unroll
            for (int n = 0; n < 2; n++) {
                int row0 = bm + wr*64 + m*16 + g*4;
                int col  = bn + wc*32 + n*16 + c;
                int z = (row0 >> 9)*8 + ((col - 2*CD) >> 6);
                int d = (col - 2*CD) & 63;
                int s0 = row0 & 511;
                float bcol = bias[col];
                us4 o;
#pragma unroll
                for (int j = 0; j < 4; j++) o[j] = f2bfbits(acc[m][n][j] + bcol);
                *(us4*)(vtb + ((size_t)z*CDH + d)*CS + s0) = o;
            }
    }
}

// ff1 with LN-staged A: out = relu(LN1(x1) @ f1w^T + f1b), bf16 -> ffb.
__global__ __launch_bounds__(512) void k_mm_ff1_ln(const float* __restrict__ tmpIn,
                                                   const float* __restrict__ Sp,
                                                   const float* __restrict__ Qp,
                                                   const float* __restrict__ lns,
                                                   const float* __restrict__ lnb,
                                                   const bf16* __restrict__ W,
                                                   const float* __restrict__ bias,
                                                   bf16* __restrict__ out) {
    __shared__ char smem[2*256*128];
    const int bm = blockIdx.y * 128, bn = blockIdx.x * 128;
    f32x4 acc[4][2] = {};
    mm_lnA_pipe(tmpIn, Sp, Qp, lns, lnb, bm, W + (size_t)bn*CD, CD, smem, acc);
    const int lane = threadIdx.x & 63, wv = threadIdx.x >> 6;
    const int wr = wv >> 2, wc = wv & 3;
    const int g = lane >> 4, c = lane & 15;
#pragma unroll
    for (int m = 0; m < 4; m++)
#pragma unroll
        for (int n = 0; n < 2; n++)
#pragma unroll
            for (int j = 0; j < 4; j++) {
                int row = bm + wr*64 + m*16 + g*4 + j;
                int col = bn + wc*32 + n*16 + c;
                float v = fmaxf(acc[m][n][j] + bias[col], 0.0f);
                out[(size_t)row*CDFF + col] = __float2bfloat16(v);
            }
}

// Residual GEMM with split-LN producer side: x = A@W^T + bias + resid ->
// tmpOut + per-(colblock,row) partial sums (plain stores, no atomics).
// RESMODE 0: resid = hres (f32, embed output). RESMODE 1: resid = LN-elem(tmpIn).
template<int RESMODE>
__global__ __launch_bounds__(512) void k_mm_res(const bf16* __restrict__ A, int K,
                                                const bf16* __restrict__ W,
                                                const float* __restrict__ bias,
                                                const float* __restrict__ hres,
                                                const float* __restrict__ tmpIn,
                                                const float* __restrict__ SpIn,
                                                const float* __restrict__ QpIn,
                                                const float* __restrict__ sIn,
                                                const float* __restrict__ bIn,
                                                float* __restrict__ tmpOut,
                                                float* __restrict__ SpOut,
                                                float* __restrict__ QpOut) {
    constexpr int BM = 64, BN = 64, TPB = 512;
    using G = MMGeom<BM,BN,TPB>;
    __shared__ char smem[4*(BM+BN)*128];
    __shared__ float lmean[64], lrstd[64];
    __shared__ float pS[4][64], pQ[4][64];
    const int bm = blockIdx.y*BM, bn = blockIdx.x*BN;
    const int tid = threadIdx.x;

    f32x4 acc[G::MR][G::NR] = {};
    mm_core_pipe<BM,BN,TPB>(A + (size_t)bm*K, K, W + (size_t)bn*K, K, K, smem, acc);

    if (RESMODE == 1) {
        if (tid < 64) {
            int row = bm + tid;
            float S=0, Q=0;
#pragma unroll
            for (int j = 0; j < 8; j++) { S += SpIn[j*MROWS + row]; Q += QpIn[j*MROWS + row]; }
            float mn = S*(1.0f/CD);
            lmean[tid] = mn;
            lrstd[tid] = rsqrtf(Q*(1.0f/CD) - mn*mn + 1e-5f);
        }
        __syncthreads();
    }
    const int lane = tid & 63, wv = tid >> 6;
    const int wr = wv >> 2, wc = wv & 3;
    const int g = lane >> 4, c = lane & 15;
    float s_[2][4], q_[2][4];
#pragma unroll
    for (int m = 0; m < 2; m++)
#pragma unroll
        for (int j = 0; j < 4; j++) {
            int rl = wr*32 + m*16 + g*4 + j;
            int col = bn + wc*16 + c;
            int row = bm + rl;
            float resid;
            if (RESMODE == 1)
                resid = (tmpIn[(size_t)row*CD + col] - lmean[rl])*lrstd[rl]*sIn[col] + bIn[col];
            else
                resid = hres[(size_t)row*CD + col];
            float x = acc[m][0][j] + bias[col] + resid;
            tmpOut[(size_t)row*CD + col] = x;
            s_[m][j] = x; q_[m][j] = x*x;
        }
#pragma unroll
    for (int m = 0; m < 2; m++)
#pragma unroll
        for (int j = 0; j < 4; j++)
#pragma unroll
            for (int off = 1; off < 16; off <<= 1) {
                s_[m][j] += __shfl_xor(s_[m][j], off);
                q_[m][j] += __shfl_xor(q_[m][j], off);
            }
    if (c == 0) {
#pragma unroll
        for (int m = 0; m < 2; m++)
#pragma unroll
            for (int j = 0; j < 4; j++) {
                int rl = wr*32 + m*16 + g*4 + j;
                pS[wc][rl] = s_[m][j]; pQ[wc][rl] = q_[m][j];
            }
    }
    __syncthreads();
    if (tid < 64) {
        SpOut[blockIdx.x*MROWS + bm + tid] = pS[0][tid]+pS[1][tid]+pS[2][tid]+pS[3][tid];
        QpOut[blockIdx.x*MROWS + bm + tid] = pQ[0][tid]+pQ[1][tid]+pQ[2][tid]+pQ[3][tid];
    }
}

// ---------------------------------------------------------------------------
// Fused attention (r9/r10 proven): 4 K/V buffers, one barrier per KV tile, defer-max.
__global__ __launch_bounds__(256) void k_attn_fused(const bf16* __restrict__ qkv,
                                                    const bf16* __restrict__ vt,
                                                    const bf16* __restrict__ bias,
                                                    bf16* __restrict__ att) {
    __shared__ char Ksm[4][16384];
    __shared__ char Vsm[4][16384];
    __shared__ char Ps[16384];

    const int z = blockIdx.y, b = z >> 3, h = z & 7;
    const int qbase = blockIdx.x * 64;
    const int tid = threadIdx.x, l = tid & 63, w = tid >> 6;
    const int g = l >> 4, c = l & 15, swz = l & 7;
    const int q_global = qbase + w*16 + c;

    const bf16* qrow = qkv + ((size_t)(b*CS + q_global))*(3*CD) + h*CDH;
    short8 bq0 = *(const short8*)(qrow + g*8);
    short8 bq1 = *(const short8*)(qrow + 32 + g*8);
    const bf16* brow = bias + ((size_t)z*CS + q_global)*CS;

    float mrun = -1e30f, lsum = 0.0f;
    f32x4 accO[4] = {};
    char* Pb = Ps + w*4096;

    auto stageKV = [&](int kv0, char* Ks, char* Vs) {
#pragma unroll
        for (int i = 0; i < 4; i++) {
            int s = i*256 + tid;
            int r = s >> 3, u = s & 7;
            const bf16* gk = qkv + ((size_t)(b*CS + kv0 + r))*(3*CD) + CD + h*CDH + ((u ^ (r&7)) * 8);
            gload_lds16(gk, Ks + (size_t)(s & ~63)*16);
        }
#pragma unroll
        for (int i = 0; i < 4; i++) {
            int s = i*256 + tid;
            int d = s >> 4, u = s & 15;
            const bf16* gv = vt + ((size_t)(z*CDH + d))*CS + kv0 + ((u ^ (d&7)) * 8);
            gload_lds16(gv, Vs + (size_t)(s & ~63)*16);
        }
    };

    stageKV(0,   Ksm[0], Vsm[0]);
    stageKV(128, Ksm[1], Vsm[1]);

    for (int t = 0; t < 4; t++) {
        int kv0 = t * 128;
        if (t < 2) stageKV((t+2)*128, Ksm[t+2], Vsm[t+2]);
        if (t == 0)      asm volatile("s_waitcnt vmcnt(32)" ::: "memory");
        else if (t == 1) asm volatile("s_waitcnt vmcnt(40)" ::: "memory");
        else if (t == 2) asm volatile("s_waitcnt vmcnt(32)" ::: "memory");
        else             asm volatile("s_waitcnt vmcnt(0)" ::: "memory");
        __builtin_amdgcn_s_barrier();
        const char* Kc = Ksm[t];
        const char* Vc = Vsm[t];

        float sv[8][4];
        float tmax = -1e30f;
#pragma unroll
        for (int n = 0; n < 8; n++) {
            int row = n*16 + c;
            short8 af0 = *(const short8*)(Kc + row*128 + ((g    ^ swz) * 16));
            short8 af1 = *(const short8*)(Kc + row*128 + (((4+g) ^ swz) * 16));
            f32x4 a = {};
            a = __builtin_amdgcn_mfma_f32_16x16x32_bf16(af0, bq0, a, 0, 0, 0);
            a = __builtin_amdgcn_mfma_f32_16x16x32_bf16(af1, bq1, a, 0, 0, 0);
            us4 b4 = *(const us4*)(brow + kv0 + n*16 + g*4);
#pragma unroll
            for (int j = 0; j < 4; j++) {
                sv[n][j] = a[j] * 0.125f + bfbits2f(b4[j]);
                tmax = fmaxf(tmax, sv[n][j]);
            }
        }
        tmax = fmaxf(tmax, __shfl_xor(tmax, 16));
        tmax = fmaxf(tmax, __shfl_xor(tmax, 32));
        if (!__all(tmax - mrun <= 8.0f)) {
            float mnew = fmaxf(mrun, tmax);
            float corr = __expf(mrun - mnew);
            lsum *= corr;
#pragma unroll
            for (int n2 = 0; n2 < 4; n2++)
#pragma unroll
                for (int j = 0; j < 4; j++) accO[n2][j] *= corr;
            mrun = mnew;
        }
        float tsum = 0.0f;
#pragma unroll
        for (int n = 0; n < 8; n++)
#pragma unroll
            for (int j = 0; j < 4; j++) {
                float e = __expf(sv[n][j] - mrun);
                sv[n][j] = e;
                tsum += e;
            }
        tsum += __shfl_xor(tsum, 16);
        tsum += __shfl_xor(tsum, 32);
        lsum += tsum;

#pragma unroll
        for (int n = 0; n < 8; n++) {
            us4 pk;
#pragma unroll
            for (int j = 0; j < 4; j++) pk[j] = f2bfbits(sv[n][j]);
            *(us4*)(Pb + c*256 + ((n*32 + g*8) ^ (swz << 4))) = pk;
        }

#pragma unroll
        for (int n2 = 0; n2 < 4; n2++) {
            int d = n2*16 + c;
#pragma unroll
            for (int kk = 0; kk < 4; kk++) {
                short8 av = *(const short8*)(Vc + d*256 + (((kk*4 + g) ^ swz) * 16));
                short8 bp = *(const short8*)(Pb + c*256 + (((kk*64 + g*16) ^ (swz << 4))));
                accO[n2] = __builtin_amdgcn_mfma_f32_16x16x32_bf16(av, bp, accO[n2], 0, 0, 0);
            }
        }
    }

    float inv = 1.0f / lsum;
    bf16* orow = att + ((size_t)(b*CS + q_global))*CD + h*CDH;
#pragma unroll
    for (int n2 = 0; n2 < 4; n2++) {
        us4 o;
#pragma unroll
        for (int j = 0; j < 4; j++) o[j] = f2bfbits(accO[n2][j] * inv);
        *(us4*)(orow + n2*16 + g*4) = o;
    }
}

// ---------------------------------------------------------------------------
__global__ void k_standardize(const float* __restrict__ x, float* __restrict__ ts,
                              float* __restrict__ fs) {
    int b = blockIdx.x, ch = blockIdx.y, tid = threadIdx.x;
    __shared__ float red[256];
    float v0 = x[(b*CS + tid)*CF + ch];
    float v1 = x[(b*CS + tid + 256)*CF + ch];
    red[tid] = v0 + v1; __syncthreads();
    for (int w = 128; w > 0; w >>= 1) { if (tid < w) red[tid] += red[tid+w]; __syncthreads(); }
    float mean = red[0] * (1.0f/CS); __syncthreads();
    float d0 = v0-mean, d1 = v1-mean;
    red[tid] = d0*d0 + d1*d1; __syncthreads();
    for (int w = 128; w > 0; w >>= 1) { if (tid < w) red[tid] += red[tid+w]; __syncthreads(); }
    float inv = rsqrtf(red[0]*(1.0f/CS) + 1e-6f);
    float* o = ch == 0 ? ts : fs;
    o[b*CS + tid] = d0*inv; o[b*CS + tid + 256] = d1*inv;
}

__global__ __launch_bounds__(256) void k_relpos(const float* __restrict__ ts, const float* __restrict__ fs,
                         const float* __restrict__ w1, const float* __restrict__ b1,
                         const float* __restrict__ w2, const float* __restrict__ b2,
                         bf16* __restrict__ bias) {
    int idx = blockIdx.x * 256 + threadIdx.x;
    int j = idx & (CS-1), i = (idx >> 9) & (CS-1), b = idx >> 18;
    float dt = ts[b*CS + i] - ts[b*CS + j];
    float df = fs[b*CS + i] - fs[b*CS + j];
    float acc[CH];
#pragma unroll
    for (int h = 0; h < CH; h++) acc[h] = b2[h];
    for (int r = 0; r < CRPH; r++) {
        float hd = fmaxf(w1[r*2]*dt + w1[r*2+1]*df + b1[r], 0.0f);
#pragma unroll
        for (int h = 0; h < CH; h++) acc[h] += w2[h*CRPH + r] * hd;
    }
#pragma unroll
    for (int h = 0; h < CH; h++) {
        float v = fminf(fmaxf(acc[h], -5.0f), 5.0f);
        bias[((size_t)(b*CH + h)*CS + i)*CS + j] = __float2bfloat16(v);
    }
}

__global__ __launch_bounds__(256) void k_embed(const float* __restrict__ x, const float* __restrict__ w,
                        const float* __restrict__ bv, float* __restrict__ h, bf16* __restrict__ hb) {
    int idx = blockIdx.x * 256 + threadIdx.x;
    int d = idx & (CD-1), m = idx >> 9;
    const float* xr = x + m*CF;
    const float* wr = w + d*CF;
    float acc = bv[d];
#pragma unroll
    for (int f = 0; f < CF; f++) acc += xr[f]*wr[f];
    h[idx] = acc; hb[idx] = __float2bfloat16(acc);
}

// one-shot conversion of all 6 layers' weights
__global__ __launch_bounds__(256) void k_wconv_all(const float* __restrict__ aiw, const float* __restrict__ aow,
                        const float* __restrict__ f1w, const float* __restrict__ f2w,
                        bf16* __restrict__ dst) {
    int lyr = blockIdx.y;
    size_t i = ((size_t)blockIdx.x * 256 + threadIdx.x) * 8;
    const float* src; size_t off;
    if (i < 786432)       { src = aiw + (size_t)lyr* 786432; off = i; }
    else if (i < 1048576) { src = aow + (size_t)lyr* 262144; off = i - 786432; }
    else if (i < 2097152) { src = f1w + (size_t)lyr*1048576; off = i - 1048576; }
    else                  { src = f2w + (size_t)lyr*1048576; off = i - 2097152; }
    short8 o;
#pragma unroll
    for (int j = 0; j < 8; j++) o[j] = __builtin_bit_cast(short, __float2bfloat16(src[off + j]));
    *(short8*)(void*)(dst + (size_t)lyr*3145728 + i) = o;
}

// per-layer fallback weight conversion
__global__ __launch_bounds__(256) void k_wconv(const float* __restrict__ a0, const float* __restrict__ a1,
                        const float* __restrict__ a2, const float* __restrict__ a3,
                        bf16* __restrict__ dst) {
    size_t i = ((size_t)blockIdx.x * 256 + threadIdx.x) * 8;
    const float* src; size_t off;
    if (i < 786432)       { src = a0; off = i; }
    else if (i < 1048576) { src = a1; off = i - 786432; }
    else if (i < 2097152) { src = a2; off = i - 1048576; }
    else                  { src = a3; off = i - 2097152; }
    short8 o;
#pragma unroll
    for (int j = 0; j < 8; j++) o[j] = __builtin_bit_cast(short, __float2bfloat16(src[off + j]));
    *(short8*)(void*)(dst + i) = o;
}

// pool with fused LN2 of the last layer: rep[b][d] = mean_s LN(x2[b,s,:])[d]
__global__ __launch_bounds__(256) void k_pool_ln(const float* __restrict__ tmp2,
                                                 const float* __restrict__ Sp,
                                                 const float* __restrict__ Qp,
                                                 const float* __restrict__ lns,
                                                 const float* __restrict__ lnb,
                                                 float* __restrict__ rep) {
    __shared__ float lmean[512], lrstd[512];
    __shared__ float red[256];
    int b = blockIdx.x, d0 = blockIdx.y*64;
    int t = threadIdx.x;
    for (int s = t; s < 512; s += 256) {
        int row = b*512 + s;
        float S=0, Q=0;
#pragma unroll
        for (int j = 0; j < 8; j++) { S += Sp[j*MROWS + row]; Q += Qp[j*MROWS + row]; }
        float mn = S*(1.0f/CD);
        lmean[s] = mn;
        lrstd[s] = rsqrtf(Q*(1.0f/CD) - mn*mn + 1e-5f);
    }
    __syncthreads();
    int dl = t & 63, sg = t >> 6, d = d0 + dl;
    float sc = lns[d], bb = lnb[d], acc = 0.0f;
    for (int s = sg*128; s < sg*128 + 128; s++)
        acc += (tmp2[(size_t)(b*512 + s)*CD + d] - lmean[s])*lrstd[s]*sc + bb;
    red[t] = acc; __syncthreads();
    if (t < 64)
        rep[b*CD + d0 + dl] = (red[t] + red[t+64] + red[t+128] + red[t+192]) * (1.0f/CS);
}

__global__ void k_fc(const float* __restrict__ rep, const float* __restrict__ fcw,
                     const float* __restrict__ fcb, float* __restrict__ out) {
    int b = blockIdx.x, cc = blockIdx.y, l = threadIdx.x;
    float acc = 0.0f;
    for (int d = l; d < CD; d += 64) acc += rep[b*CD + d] * fcw[cc*CD + d];
    for (int o = 32; o > 0; o >>= 1) acc += __shfl_xor(acc, o);
    if (l == 0) out[b*CNC + cc] = acc + fcb[cc];
}

// ---------------------------------------------------------------------------
extern "C" void kernel_launch(void* const* d_in, const int* in_sizes, int n_in,
                              void* d_out, int out_size, void* d_ws, size_t ws_size,
                              hipStream_t stream) {
    const float* x   = (const float*)d_in[0];
    const float* rw1 = (const float*)d_in[1];
    const float* rb1 = (const float*)d_in[2];
    const float* rw2 = (const float*)d_in[3];
    const float* rb2 = (const float*)d_in[4];
    const float* emw = (const float*)d_in[5];
    const float* emb = (const float*)d_in[6];
    const float* aiw = (const float*)d_in[7];
    const float* aib = (const float*)d_in[8];
    const float* aow = (const float*)d_in[9];
    const float* aob = (const float*)d_in[10];
    const float* f1w = (const float*)d_in[11];
    const float* f1b = (const float*)d_in[12];
    const float* f2w = (const float*)d_in[13];
    const float* f2b = (const float*)d_in[14];
    const float* l1s = (const float*)d_in[15];
    const float* l1b = (const float*)d_in[16];
    const float* l2s = (const float*)d_in[17];
    const float* l2b = (const float*)d_in[18];
    const float* fcw = (const float*)d_in[19];
    const float* fcb = (const float*)d_in[20];
    float* out = (float*)d_out;

    char* p = (char*)d_ws;
    auto alloc = [&](size_t bytes) { char* r = p; p += (bytes + 255) & ~(size_t)255; return r; };
    bf16*  biasb = (bf16*)alloc((size_t)CB*CH*CS*CS*2);    // 16.78 MB
    float* h     = (float*)alloc((size_t)MROWS*CD*4);      // 4.19 MB (embed f32)
    bf16*  hb    = (bf16*)alloc((size_t)MROWS*CD*2);       // 2.10 MB (embed bf16)
    bf16*  qkvb  = (bf16*)alloc((size_t)MROWS*3*CD*2);     // 6.29 MB
    bf16*  vtb   = (bf16*)alloc((size_t)CB*CH*CDH*CS*2);   // 2.10 MB
    bf16*  attb  = (bf16*)alloc((size_t)MROWS*CD*2);       // 2.10 MB
    bf16*  ffb   = (bf16*)alloc((size_t)MROWS*CDFF*2);     // 8.39 MB
    float* tmp1  = (float*)alloc((size_t)MROWS*CD*4);      // 4.19 MB
    float* tmp2  = (float*)alloc((size_t)MROWS*CD*4);      // 4.19 MB
    float* Sp1   = (float*)alloc((size_t)8*MROWS*4);       // 64 KB
    float* Qp1   = (float*)alloc((size_t)8*MROWS*4);
    float* Sp2   = (float*)alloc((size_t)8*MROWS*4);
    float* Qp2   = (float*)alloc((size_t)8*MROWS*4);
    bf16*  wl    = (bf16*)alloc((size_t)3145728*2);        // 6.29 MB (fallback)
    float* rep   = (float*)alloc((size_t)CB*CD*4);
    float* ts    = (float*)alloc(CB*CS*4);
    float* fs    = (float*)alloc(CB*CS*4);

    size_t used = (size_t)(p - (char*)d_ws);
    const size_t WLE = 3145728;
    bool oneshot = (ws_size > used) && ((ws_size - used) >= (size_t)CL*WLE*2 + 256);
    bf16* wlall = (bf16*)alloc(oneshot ? (size_t)CL*WLE*2 : 0);

    const int M = MROWS;

    k_standardize<<<dim3(CB,2), 256, 0, stream>>>(x, ts, fs);
    k_relpos<<<(CB*CS*CS)/256, 256, 0, stream>>>(ts, fs, rw1, rb1, rw2, rb2, biasb);
    k_embed<<<(M*CD)/256, 256, 0, stream>>>(x, emw, emb, h, hb);
    if (oneshot)
        k_wconv_all<<<dim3(1536, CL), 256, 0, stream>>>(aiw, aow, f1w, f2w, wlall);

    for (int l = 0; l < CL; l++) {
        const bf16* wbase = oneshot ? (wlall + (size_t)l*WLE) : wl;
        if (!oneshot)
            k_wconv<<<1536, 256, 0, stream>>>(aiw + (size_t)l*786432, aow + (size_t)l*262144,
                                              f1w + (size_t)l*1048576, f2w + (size_t)l*1048576, wl);
        const bf16* wl_aiw = wbase;
        const bf16* wl_aow = wbase + 786432;
        const bf16* wl_f1w = wbase + 1048576;
        const bf16* wl_f2w = wbase + 2097152;

        if (l == 0)
            k_mm_qkv<<<dim3(12,16), 512, 0, stream>>>(hb, wl_aiw, aib, qkvb, vtb);
        else
            k_mm_qkv_ln<<<dim3(12,16), 512, 0, stream>>>(tmp2, Sp2, Qp2,
                l2s + (size_t)(l-1)*CD, l2b + (size_t)(l-1)*CD,
                wl_aiw, aib + (size_t)l*3*CD, qkvb, vtb);

        k_attn_fused<<<dim3(CS/64, CB*CH), 256, 0, stream>>>(qkvb, vtb, biasb, attb);

        if (l == 0)
            k_mm_res<0><<<dim3(8,32), 512, 0, stream>>>(attb, CD, wl_aow, aob,
                h, nullptr, nullptr, nullptr, nullptr, nullptr, tmp1, Sp1, Qp1);
        else
            k_mm_res<1><<<dim3(8,32), 512, 0, stream>>>(attb, CD, wl_aow,
                aob + (size_t)l*CD, nullptr, tmp2, Sp2, Qp2,
                l2s + (size_t)(l-1)*CD, l2b + (size_t)(l-1)*CD, tmp1, Sp1, Qp1);

        k_mm_ff1_ln<<<dim3(16,16), 512, 0, stream>>>(tmp1, Sp1, Qp1,
            l1s + (size_t)l*CD, l1b + (size_t)l*CD, wl_f1w, f1b + (size_t)l*CDFF, ffb);

        k_mm_res<1><<<dim3(8,32), 512, 0, stream>>>(ffb, CDFF, wl_f2w,
            f2b + (size_t)l*CD, nullptr, tmp1, Sp1, Qp1,
            l1s + (size_t)l*CD, l1b + (size_t)l*CD, tmp2, Sp2, Qp2);
    }

    k_pool_ln<<<dim3(CB, CD/64), 256, 0, stream>>>(tmp2, Sp2, Qp2,
        l2s + (size_t)(CL-1)*CD, l2b + (size_t)(CL-1)*CD, rep);
    k_fc<<<dim3(CB, CNC), 64, 0, stream>>>(rep, fcw, fcb, out);
}

// Round 12
// 464.962 us; speedup vs baseline: 1.7917x; 1.1614x over previous
//
#include <hip/hip_runtime.h>
#include <hip/hip_bf16.h>
#include <stdint.h>

using short8 = __attribute__((ext_vector_type(8))) short;
using us4    = __attribute__((ext_vector_type(4))) unsigned short;
using f32x4  = __attribute__((ext_vector_type(4))) float;
using bf16   = __hip_bfloat16;

constexpr int CB=4, CS=512, CF=16, CD=512, CH=8, CL=6, CDFF=2048, CNC=12, CRPH=64, CDH=64;
constexpr int MROWS = CB*CS;   // 2048

__device__ inline void gload_lds16(const void* g, void* l) {
    __builtin_amdgcn_global_load_lds((const __attribute__((address_space(1))) void*)g,
                                     (__attribute__((address_space(3))) void*)l, 16, 0, 0);
}
__device__ inline float bfbits2f(unsigned short u) {
    return __uint_as_float(((uint32_t)u) << 16);
}
__device__ inline unsigned short f2bfbits(float f) {
    return __builtin_bit_cast(unsigned short, __float2bfloat16(f));
}

// ---------------------------------------------------------------------------
// Geometry: TPB=256, BM=64, 4 waves side-by-side over columns (WC=4, WR=1).
// Small LDS (2-deep ring) -> 3-5 blocks/CU for inter-block wave overlap.
template<int BM, int BN>
struct MMG {
    static constexpr int CSP = BN/4;            // cols per wave
    static constexpr int MR  = BM/16;
    static constexpr int NR  = CSP/16;
    static constexpr int NLD = (BM+BN)*128/(256*16);  // gload issues/thread/stage
};

// BK=64 staging: LDS rows 128 B, XOR swizzle (slot ^= row&7); linear LDS dest +
// inverse-swizzled global source (both-sides rule).
template<int BM, int BN>
__device__ inline void stage_tile(const bf16* A, int lda, const bf16* W, int ldw, int k0,
                                  char* As, char* Bs) {
    constexpr int AC = (BM*128)/(256*16);
    constexpr int BC = (BN*128)/(256*16);
    const int tid = threadIdx.x;
#pragma unroll
    for (int i = 0; i < AC; i++) {
        int s = i*256 + tid;
        int r = s >> 3, u = s & 7;
        const char* gp = (const char*)(A + (size_t)r*lda + k0) + ((u ^ (r&7))*16);
        gload_lds16(gp, As + (size_t)(s & ~63)*16);
    }
#pragma unroll
    for (int i = 0; i < BC; i++) {
        int s = i*256 + tid;
        int r = s >> 3, u = s & 7;
        const char* gp = (const char*)(W + (size_t)r*ldw + k0) + ((u ^ (r&7))*16);
        gload_lds16(gp, Bs + (size_t)(s & ~63)*16);
    }
}

template<int BM, int BN>
__device__ inline void compute_tile64(const char* As, const char* Bs,
                                      int wc, int c, int g,
                                      f32x4 (&acc)[MMG<BM,BN>::MR][MMG<BM,BN>::NR]) {
    using G = MMG<BM,BN>;
#pragma unroll
    for (int kk = 0; kk < 2; kk++) {
        short8 af[G::MR], bfv[G::NR];
#pragma unroll
        for (int m = 0; m < G::MR; m++) {
            int row = m*16 + c;
            af[m] = *(const short8*)(As + row*128 + (((kk*4+g) ^ (row&7))*16));
        }
#pragma unroll
        for (int n = 0; n < G::NR; n++) {
            int row = wc*G::CSP + n*16 + c;
            bfv[n] = *(const short8*)(Bs + row*128 + (((kk*4+g) ^ (row&7))*16));
        }
#pragma unroll
        for (int m = 0; m < G::MR; m++)
#pragma unroll
            for (int n = 0; n < G::NR; n++)
                acc[m][n] = __builtin_amdgcn_mfma_f32_16x16x32_bf16(af[m], bfv[n], acc[m][n], 0, 0, 0);
    }
}

// 2-deep ping-pong, counted vmcnt (r6-proven scheme).
template<int BM, int BN>
__device__ inline void mm_core_pipe(const bf16* A, int lda, const bf16* W, int ldw, int K,
                                    char* smem,
                                    f32x4 (&acc)[MMG<BM,BN>::MR][MMG<BM,BN>::NR]) {
    using G = MMG<BM,BN>;
    constexpr int SSZ = (BM+BN)*128;
    const int lane = threadIdx.x & 63, wv = threadIdx.x >> 6;
    const int g = lane >> 4, c = lane & 15;

    const int nk = K >> 6;
    stage_tile<BM,BN>(A, lda, W, ldw, 0, smem, smem + BM*128);
    for (int t = 0; t < nk; t++) {
        char* bc = smem + (size_t)(t & 1)*SSZ;
        if (t + 1 < nk) {
            char* bs = smem + (size_t)((t+1) & 1)*SSZ;
            stage_tile<BM,BN>(A, lda, W, ldw, (t+1)*64, bs, bs + BM*128);
            asm volatile("s_waitcnt vmcnt(%0)" :: "n"(G::NLD) : "memory");
        } else {
            asm volatile("s_waitcnt vmcnt(0)" ::: "memory");
        }
        __builtin_amdgcn_s_barrier();
        compute_tile64<BM,BN>(bc, bc + BM*128, wv, c, g, acc);
        __builtin_amdgcn_s_barrier();
    }
}

// EPI: 0 = bf16+bias ; 1 = bf16+bias+relu ; 2 = f32+bias (bias only on kz==0)
template<int BM, int BN, int EPI, int KSPLIT>
__global__ __launch_bounds__(256) void k_mm(const bf16* __restrict__ A, int lda,
                                            const bf16* __restrict__ W, int ldw,
                                            const float* __restrict__ bias,
                                            bf16* __restrict__ Cb, float* __restrict__ Cf,
                                            int ldc, int K) {
    using G = MMG<BM,BN>;
    __shared__ char smem[2*(BM+BN)*128];
    const int bm = blockIdx.y * BM, bn = blockIdx.x * BN;
    const int kz = (KSPLIT > 1) ? blockIdx.z : 0;
    const int Kper = K / KSPLIT;
    f32x4 acc[G::MR][G::NR] = {};
    mm_core_pipe<BM,BN>(A + (size_t)bm*lda + kz*Kper, lda,
                        W + (size_t)bn*ldw + kz*Kper, ldw, Kper, smem, acc);
    const int lane = threadIdx.x & 63, wv = threadIdx.x >> 6;
    const int g = lane >> 4, c = lane & 15;
    float* Cfz = Cf + (size_t)kz * MROWS * ldc;
#pragma unroll
    for (int m = 0; m < G::MR; m++)
#pragma unroll
        for (int n = 0; n < G::NR; n++)
#pragma unroll
            for (int j = 0; j < 4; j++) {
                int row = bm + m*16 + g*4 + j;
                int col = bn + wv*G::CSP + n*16 + c;
                float v = acc[m][n][j] + ((kz == 0) ? bias[col] : 0.0f);
                if (EPI == 1) v = fmaxf(v, 0.0f);
                if (EPI == 2) Cfz[(size_t)row*ldc + col] = v;
                else          Cb[(size_t)row*ldc + col] = __float2bfloat16(v);
            }
}

// qkv GEMM (BM=64, BN=128): Q,K -> qkvb; V cols written transposed into vtb.
__global__ __launch_bounds__(256) void k_mm_qkv(const bf16* __restrict__ A,
                                                const bf16* __restrict__ W,
                                                const float* __restrict__ bias,
                                                bf16* __restrict__ qkvb,
                                                bf16* __restrict__ vtb) {
    constexpr int BM = 64, BN = 128;
    using G = MMG<BM,BN>;
    __shared__ char smem[2*(BM+BN)*128];
    const int bm = blockIdx.y * BM, bn = blockIdx.x * BN;
    f32x4 acc[G::MR][G::NR] = {};
    mm_core_pipe<BM,BN>(A + (size_t)bm*CD, CD, W + (size_t)bn*CD, CD, CD, smem, acc);
    const int lane = threadIdx.x & 63, wv = threadIdx.x >> 6;
    const int g = lane >> 4, c = lane & 15;
    if (bn < 2*CD) {
#pragma unroll
        for (int m = 0; m < G::MR; m++)
#pragma unroll
            for (int n = 0; n < G::NR; n++)
#pragma unroll
                for (int j = 0; j < 4; j++) {
                    int row = bm + m*16 + g*4 + j;
                    int col = bn + wv*G::CSP + n*16 + c;
                    qkvb[(size_t)row*(3*CD) + col] = __float2bfloat16(acc[m][n][j] + bias[col]);
                }
    } else {
#pragma unroll
        for (int m = 0; m < G::MR; m++)
#pragma unroll
            for (int n = 0; n < G::NR; n++) {
                int row0 = bm + m*16 + g*4;
                int col  = bn + wv*G::CSP + n*16 + c;
                int z = (row0 >> 9)*8 + ((col - 2*CD) >> 6);
                int d = (col - 2*CD) & 63;
                int s0 = row0 & 511;
                float bcol = bias[col];
                us4 o;
#pragma unroll
                for (int j = 0; j < 4; j++) o[j] = f2bfbits(acc[m][n][j] + bcol);
                *(us4*)(vtb + ((size_t)z*CDH + d)*CS + s0) = o;
            }
    }
}

// ---------------------------------------------------------------------------
// Fused attention (r9-proven): 4 K/V buffers, one barrier per KV tile, defer-max.
__global__ __launch_bounds__(256) void k_attn_fused(const bf16* __restrict__ qkv,
                                                    const bf16* __restrict__ vt,
                                                    const bf16* __restrict__ bias,
                                                    bf16* __restrict__ att) {
    __shared__ char Ksm[4][16384];
    __shared__ char Vsm[4][16384];
    __shared__ char Ps[16384];

    const int z = blockIdx.y, b = z >> 3, h = z & 7;
    const int qbase = blockIdx.x * 64;
    const int tid = threadIdx.x, l = tid & 63, w = tid >> 6;
    const int g = l >> 4, c = l & 15, swz = l & 7;
    const int q_global = qbase + w*16 + c;

    const bf16* qrow = qkv + ((size_t)(b*CS + q_global))*(3*CD) + h*CDH;
    short8 bq0 = *(const short8*)(qrow + g*8);
    short8 bq1 = *(const short8*)(qrow + 32 + g*8);
    const bf16* brow = bias + ((size_t)z*CS + q_global)*CS;

    float mrun = -1e30f, lsum = 0.0f;
    f32x4 accO[4] = {};
    char* Pb = Ps + w*4096;

    auto stageKV = [&](int kv0, char* Ks, char* Vs) {
#pragma unroll
        for (int i = 0; i < 4; i++) {
            int s = i*256 + tid;
            int r = s >> 3, u = s & 7;
            const bf16* gk = qkv + ((size_t)(b*CS + kv0 + r))*(3*CD) + CD + h*CDH + ((u ^ (r&7)) * 8);
            gload_lds16(gk, Ks + (size_t)(s & ~63)*16);
        }
#pragma unroll
        for (int i = 0; i < 4; i++) {
            int s = i*256 + tid;
            int d = s >> 4, u = s & 15;
            const bf16* gv = vt + ((size_t)(z*CDH + d))*CS + kv0 + ((u ^ (d&7)) * 8);
            gload_lds16(gv, Vs + (size_t)(s & ~63)*16);
        }
    };

    stageKV(0,   Ksm[0], Vsm[0]);
    stageKV(128, Ksm[1], Vsm[1]);

    for (int t = 0; t < 4; t++) {
        int kv0 = t * 128;
        if (t < 2) stageKV((t+2)*128, Ksm[t+2], Vsm[t+2]);
        if (t == 0)      asm volatile("s_waitcnt vmcnt(32)" ::: "memory");
        else if (t == 1) asm volatile("s_waitcnt vmcnt(40)" ::: "memory");
        else if (t == 2) asm volatile("s_waitcnt vmcnt(32)" ::: "memory");
        else             asm volatile("s_waitcnt vmcnt(0)" ::: "memory");
        __builtin_amdgcn_s_barrier();
        const char* Kc = Ksm[t];
        const char* Vc = Vsm[t];

        float sv[8][4];
        float tmax = -1e30f;
#pragma unroll
        for (int n = 0; n < 8; n++) {
            int row = n*16 + c;
            short8 af0 = *(const short8*)(Kc + row*128 + ((g    ^ swz) * 16));
            short8 af1 = *(const short8*)(Kc + row*128 + (((4+g) ^ swz) * 16));
            f32x4 a = {};
            a = __builtin_amdgcn_mfma_f32_16x16x32_bf16(af0, bq0, a, 0, 0, 0);
            a = __builtin_amdgcn_mfma_f32_16x16x32_bf16(af1, bq1, a, 0, 0, 0);
            us4 b4 = *(const us4*)(brow + kv0 + n*16 + g*4);
#pragma unroll
            for (int j = 0; j < 4; j++) {
                sv[n][j] = a[j] * 0.125f + bfbits2f(b4[j]);
                tmax = fmaxf(tmax, sv[n][j]);
            }
        }
        tmax = fmaxf(tmax, __shfl_xor(tmax, 16));
        tmax = fmaxf(tmax, __shfl_xor(tmax, 32));
        if (!__all(tmax - mrun <= 8.0f)) {
            float mnew = fmaxf(mrun, tmax);
            float corr = __expf(mrun - mnew);
            lsum *= corr;
#pragma unroll
            for (int n2 = 0; n2 < 4; n2++)
#pragma unroll
                for (int j = 0; j < 4; j++) accO[n2][j] *= corr;
            mrun = mnew;
        }
        float tsum = 0.0f;
#pragma unroll
        for (int n = 0; n < 8; n++)
#pragma unroll
            for (int j = 0; j < 4; j++) {
                float e = __expf(sv[n][j] - mrun);
                sv[n][j] = e;
                tsum += e;
            }
        tsum += __shfl_xor(tsum, 16);
        tsum += __shfl_xor(tsum, 32);
        lsum += tsum;

#pragma unroll
        for (int n = 0; n < 8; n++) {
            us4 pk;
#pragma unroll
            for (int j = 0; j < 4; j++) pk[j] = f2bfbits(sv[n][j]);
            *(us4*)(Pb + c*256 + ((n*32 + g*8) ^ (swz << 4))) = pk;
        }

#pragma unroll
        for (int n2 = 0; n2 < 4; n2++) {
            int d = n2*16 + c;
#pragma unroll
            for (int kk = 0; kk < 4; kk++) {
                short8 av = *(const short8*)(Vc + d*256 + (((kk*4 + g) ^ swz) * 16));
                short8 bp = *(const short8*)(Pb + c*256 + (((kk*64 + g*16) ^ (swz << 4))));
                accO[n2] = __builtin_amdgcn_mfma_f32_16x16x32_bf16(av, bp, accO[n2], 0, 0, 0);
            }
        }
    }

    float inv = 1.0f / lsum;
    bf16* orow = att + ((size_t)(b*CS + q_global))*CD + h*CDH;
#pragma unroll
    for (int n2 = 0; n2 < 4; n2++) {
        us4 o;
#pragma unroll
        for (int j = 0; j < 4; j++) o[j] = f2bfbits(accO[n2][j] * inv);
        *(us4*)(orow + n2*16 + g*4) = o;
    }
}

// ---------------------------------------------------------------------------
__global__ void k_standardize(const float* __restrict__ x, float* __restrict__ ts,
                              float* __restrict__ fs) {
    int b = blockIdx.x, ch = blockIdx.y, tid = threadIdx.x;
    __shared__ float red[256];
    float v0 = x[(b*CS + tid)*CF + ch];
    float v1 = x[(b*CS + tid + 256)*CF + ch];
    red[tid] = v0 + v1; __syncthreads();
    for (int w = 128; w > 0; w >>= 1) { if (tid < w) red[tid] += red[tid+w]; __syncthreads(); }
    float mean = red[0] * (1.0f/CS); __syncthreads();
    float d0 = v0-mean, d1 = v1-mean;
    red[tid] = d0*d0 + d1*d1; __syncthreads();
    for (int w = 128; w > 0; w >>= 1) { if (tid < w) red[tid] += red[tid+w]; __syncthreads(); }
    float inv = rsqrtf(red[0]*(1.0f/CS) + 1e-6f);
    float* o = ch == 0 ? ts : fs;
    o[b*CS + tid] = d0*inv; o[b*CS + tid + 256] = d1*inv;
}

__global__ __launch_bounds__(256) void k_relpos(const float* __restrict__ ts, const float* __restrict__ fs,
                         const float* __restrict__ w1, const float* __restrict__ b1,
                         const float* __restrict__ w2, const float* __restrict__ b2,
                         bf16* __restrict__ bias) {
    int idx = blockIdx.x * 256 + threadIdx.x;
    int j = idx & (CS-1), i = (idx >> 9) & (CS-1), b = idx >> 18;
    float dt = ts[b*CS + i] - ts[b*CS + j];
    float df = fs[b*CS + i] - fs[b*CS + j];
    float acc[CH];
#pragma unroll
    for (int h = 0; h < CH; h++) acc[h] = b2[h];
    for (int r = 0; r < CRPH; r++) {
        float hd = fmaxf(w1[r*2]*dt + w1[r*2+1]*df + b1[r], 0.0f);
#pragma unroll
        for (int h = 0; h < CH; h++) acc[h] += w2[h*CRPH + r] * hd;
    }
#pragma unroll
    for (int h = 0; h < CH; h++) {
        float v = fminf(fmaxf(acc[h], -5.0f), 5.0f);
        bias[((size_t)(b*CH + h)*CS + i)*CS + j] = __float2bfloat16(v);
    }
}

__global__ __launch_bounds__(256) void k_embed(const float* __restrict__ x, const float* __restrict__ w,
                        const float* __restrict__ bv, float* __restrict__ h, bf16* __restrict__ hb) {
    int idx = blockIdx.x * 256 + threadIdx.x;
    int d = idx & (CD-1), m = idx >> 9;
    const float* xr = x + m*CF;
    const float* wr = w + d*CF;
    float acc = bv[d];
#pragma unroll
    for (int f = 0; f < CF; f++) acc += xr[f]*wr[f];
    h[idx] = acc; hb[idx] = __float2bfloat16(acc);
}

// residual + LN, wave-per-row, vectorized, no LDS. grid = M/4, 256 threads.
template<int NADD>
__global__ __launch_bounds__(256) void k_ln(float* __restrict__ h, const float* __restrict__ a0,
                     const float* __restrict__ a1,
                     const float* __restrict__ s, const float* __restrict__ bv, bf16* __restrict__ hb) {
    const int w = threadIdx.x >> 6, l = threadIdx.x & 63;
    const int row = blockIdx.x*4 + w;
    float* hr = h + (size_t)row*CD;
    const float* ar = a0 + (size_t)row*CD;
    const float* a1r = (NADD == 2) ? (a1 + (size_t)row*CD) : nullptr;

    float v[8];
    {
        float4 h0 = ((const float4*)hr)[l*2],  h1 = ((const float4*)hr)[l*2+1];
        float4 b0 = ((const float4*)ar)[l*2],  b1 = ((const float4*)ar)[l*2+1];
        v[0]=h0.x+b0.x; v[1]=h0.y+b0.y; v[2]=h0.z+b0.z; v[3]=h0.w+b0.w;
        v[4]=h1.x+b1.x; v[5]=h1.y+b1.y; v[6]=h1.z+b1.z; v[7]=h1.w+b1.w;
        if (NADD == 2) {
            float4 c0 = ((const float4*)a1r)[l*2], c1 = ((const float4*)a1r)[l*2+1];
            v[0]+=c0.x; v[1]+=c0.y; v[2]+=c0.z; v[3]+=c0.w;
            v[4]+=c1.x; v[5]+=c1.y; v[6]+=c1.z; v[7]+=c1.w;
        }
    }
    float sum = 0.f, sq = 0.f;
#pragma unroll
    for (int i = 0; i < 8; i++) { sum += v[i]; sq += v[i]*v[i]; }
#pragma unroll
    for (int off = 1; off < 64; off <<= 1) {
        sum += __shfl_xor(sum, off);
        sq  += __shfl_xor(sq, off);
    }
    float mean = sum * (1.0f/CD);
    float var  = sq * (1.0f/CD) - mean*mean;
    float rstd = rsqrtf(var + 1e-5f);

    float4 s0 = ((const float4*)s)[l*2],  s1 = ((const float4*)s)[l*2+1];
    float4 g0 = ((const float4*)bv)[l*2], g1 = ((const float4*)bv)[l*2+1];
    float o[8];
    o[0]=(v[0]-mean)*rstd*s0.x+g0.x; o[1]=(v[1]-mean)*rstd*s0.y+g0.y;
    o[2]=(v[2]-mean)*rstd*s0.z+g0.z; o[3]=(v[3]-mean)*rstd*s0.w+g0.w;
    o[4]=(v[4]-mean)*rstd*s1.x+g1.x; o[5]=(v[5]-mean)*rstd*s1.y+g1.y;
    o[6]=(v[6]-mean)*rstd*s1.z+g1.z; o[7]=(v[7]-mean)*rstd*s1.w+g1.w;

    ((float4*)hr)[l*2]   = make_float4(o[0],o[1],o[2],o[3]);
    ((float4*)hr)[l*2+1] = make_float4(o[4],o[5],o[6],o[7]);
    short8 ob;
#pragma unroll
    for (int i = 0; i < 8; i++) ob[i] = (short)f2bfbits(o[i]);
    *(short8*)(hb + (size_t)row*CD + l*8) = ob;
}

// one-shot conversion of all 6 layers' weights
__global__ __launch_bounds__(256) void k_wconv_all(const float* __restrict__ aiw, const float* __restrict__ aow,
                        const float* __restrict__ f1w, const float* __restrict__ f2w,
                        bf16* __restrict__ dst) {
    int lyr = blockIdx.y;
    size_t i = ((size_t)blockIdx.x * 256 + threadIdx.x) * 8;
    const float* src; size_t off;
    if (i < 786432)       { src = aiw + (size_t)lyr* 786432; off = i; }
    else if (i < 1048576) { src = aow + (size_t)lyr* 262144; off = i - 786432; }
    else if (i < 2097152) { src = f1w + (size_t)lyr*1048576; off = i - 1048576; }
    else                  { src = f2w + (size_t)lyr*1048576; off = i - 2097152; }
    short8 o;
#pragma unroll
    for (int j = 0; j < 8; j++) o[j] = __builtin_bit_cast(short, __float2bfloat16(src[off + j]));
    *(short8*)(void*)(dst + (size_t)lyr*3145728 + i) = o;
}

// per-layer fallback weight conversion
__global__ __launch_bounds__(256) void k_wconv(const float* __restrict__ a0, const float* __restrict__ a1,
                        const float* __restrict__ a2, const float* __restrict__ a3,
                        bf16* __restrict__ dst) {
    size_t i = ((size_t)blockIdx.x * 256 + threadIdx.x) * 8;
    const float* src; size_t off;
    if (i < 786432)       { src = a0; off = i; }
    else if (i < 1048576) { src = a1; off = i - 786432; }
    else if (i < 2097152) { src = a2; off = i - 1048576; }
    else                  { src = a3; off = i - 2097152; }
    short8 o;
#pragma unroll
    for (int j = 0; j < 8; j++) o[j] = __builtin_bit_cast(short, __float2bfloat16(src[off + j]));
    *(short8*)(void*)(dst + i) = o;
}

// pool + fc fused: grid (CB), 256 threads.
__global__ __launch_bounds__(256) void k_poolfc(const float* __restrict__ h,
                                                const float* __restrict__ fcw,
                                                const float* __restrict__ fcb,
                                                float* __restrict__ out) {
    __shared__ float rep[CD];
    int b = blockIdx.x, t = threadIdx.x;
    // pool: each thread owns 2 columns
    float a0 = 0.f, a1 = 0.f;
    for (int s = 0; s < CS; s++) {
        const float* row = h + (size_t)(b*CS + s)*CD;
        a0 += row[t];
        a1 += row[t + 256];
    }
    rep[t] = a0 * (1.0f/CS);
    rep[t + 256] = a1 * (1.0f/CS);
    __syncthreads();
    // fc: wave w handles classes 3w..3w+2
    int w = t >> 6, l = t & 63;
    for (int cc = w*3; cc < w*3 + 3 && cc < CNC; cc++) {
        float acc = 0.f;
        for (int d = l; d < CD; d += 64) acc += rep[d] * fcw[cc*CD + d];
        for (int o = 32; o > 0; o >>= 1) acc += __shfl_xor(acc, o);
        if (l == 0) out[b*CNC + cc] = acc + fcb[cc];
    }
}

// ---------------------------------------------------------------------------
extern "C" void kernel_launch(void* const* d_in, const int* in_sizes, int n_in,
                              void* d_out, int out_size, void* d_ws, size_t ws_size,
                              hipStream_t stream) {
    const float* x   = (const float*)d_in[0];
    const float* rw1 = (const float*)d_in[1];
    const float* rb1 = (const float*)d_in[2];
    const float* rw2 = (const float*)d_in[3];
    const float* rb2 = (const float*)d_in[4];
    const float* emw = (const float*)d_in[5];
    const float* emb = (const float*)d_in[6];
    const float* aiw = (const float*)d_in[7];
    const float* aib = (const float*)d_in[8];
    const float* aow = (const float*)d_in[9];
    const float* aob = (const float*)d_in[10];
    const float* f1w = (const float*)d_in[11];
    const float* f1b = (const float*)d_in[12];
    const float* f2w = (const float*)d_in[13];
    const float* f2b = (const float*)d_in[14];
    const float* l1s = (const float*)d_in[15];
    const float* l1b = (const float*)d_in[16];
    const float* l2s = (const float*)d_in[17];
    const float* l2b = (const float*)d_in[18];
    const float* fcw = (const float*)d_in[19];
    const float* fcb = (const float*)d_in[20];
    float* out = (float*)d_out;

    char* p = (char*)d_ws;
    auto alloc = [&](size_t bytes) { char* r = p; p += (bytes + 255) & ~(size_t)255; return r; };
    bf16*  biasb = (bf16*)alloc((size_t)CB*CH*CS*CS*2);    // 16.78 MB
    float* h     = (float*)alloc((size_t)MROWS*CD*4);      // 4.19 MB
    bf16*  hb    = (bf16*)alloc((size_t)MROWS*CD*2);       // 2.10 MB
    bf16*  qkvb  = (bf16*)alloc((size_t)MROWS*3*CD*2);     // 6.29 MB
    bf16*  vtb   = (bf16*)alloc((size_t)CB*CH*CDH*CS*2);   // 2.10 MB
    bf16*  attb  = (bf16*)alloc((size_t)MROWS*CD*2);       // 2.10 MB
    float* tmp   = (float*)alloc((size_t)2*MROWS*CD*4);    // 8.39 MB (2 split-K slabs)
    bf16*  ffb   = (bf16*)alloc((size_t)MROWS*CDFF*2);     // 8.39 MB
    bf16*  wl    = (bf16*)alloc((size_t)3145728*2);        // 6.29 MB (fallback)
    float* ts    = (float*)alloc(CB*CS*4);
    float* fs    = (float*)alloc(CB*CS*4);

    size_t used = (size_t)(p - (char*)d_ws);
    const size_t WLE = 3145728;
    bool oneshot = (ws_size > used) && ((ws_size - used) >= (size_t)CL*WLE*2 + 256);
    bf16* wlall = (bf16*)alloc(oneshot ? (size_t)CL*WLE*2 : 0);

    const int M = MROWS;
    float* tmp2 = tmp + (size_t)M*CD;

    k_standardize<<<dim3(CB,2), 256, 0, stream>>>(x, ts, fs);
    k_relpos<<<(CB*CS*CS)/256, 256, 0, stream>>>(ts, fs, rw1, rb1, rw2, rb2, biasb);
    k_embed<<<(M*CD)/256, 256, 0, stream>>>(x, emw, emb, h, hb);
    if (oneshot)
        k_wconv_all<<<dim3(1536, CL), 256, 0, stream>>>(aiw, aow, f1w, f2w, wlall);

    for (int l = 0; l < CL; l++) {
        const bf16* wbase = oneshot ? (wlall + (size_t)l*WLE) : wl;
        if (!oneshot)
            k_wconv<<<1536, 256, 0, stream>>>(aiw + (size_t)l*786432, aow + (size_t)l*262144,
                                              f1w + (size_t)l*1048576, f2w + (size_t)l*1048576, wl);
        const bf16* wl_aiw = wbase;
        const bf16* wl_aow = wbase + 786432;
        const bf16* wl_f1w = wbase + 1048576;
        const bf16* wl_f2w = wbase + 2097152;

        // qkv = h @ aiw^T + aib : 64x128 tiles -> 384 blocks (1.5/CU)
        k_mm_qkv<<<dim3(12, 32), 256, 0, stream>>>(hb, wl_aiw, aib + (size_t)l*3*CD, qkvb, vtb);
        // fused attention (256 blocks)
        k_attn_fused<<<dim3(CS/64, CB*CH), 256, 0, stream>>>(qkvb, vtb, biasb, attb);
        // out projection: 64x64, split-K2 -> 512 blocks (2/CU)
        k_mm<64,64,2,2><<<dim3(8,32,2), 256, 0, stream>>>(attb, CD, wl_aow, CD,
                                                          aob + (size_t)l*CD, nullptr, tmp, CD, CD);
        k_ln<2><<<M/4, 256, 0, stream>>>(h, tmp, tmp2, l1s + (size_t)l*CD, l1b + (size_t)l*CD, hb);
        // ff1 (relu): 64x128 -> 512 blocks (2/CU)
        k_mm<64,128,1,1><<<dim3(16,32), 256, 0, stream>>>(hb, CD, wl_f1w, CD,
                                                          f1b + (size_t)l*CDFF, ffb, nullptr, CDFF, CD);
        // ff2: 64x64 split-K2 -> 512 blocks
        k_mm<64,64,2,2><<<dim3(8,32,2), 256, 0, stream>>>(ffb, CDFF, wl_f2w, CDFF,
                                                          f2b + (size_t)l*CD, nullptr, tmp, CD, CDFF);
        k_ln<2><<<M/4, 256, 0, stream>>>(h, tmp, tmp2, l2s + (size_t)l*CD, l2b + (size_t)l*CD, hb);
    }

    k_poolfc<<<CB, 256, 0, stream>>>(h, fcw, fcb, out);
}

// Round 13
// 447.239 us; speedup vs baseline: 1.8627x; 1.0396x over previous
//
#include <hip/hip_runtime.h>
#include <hip/hip_bf16.h>
#include <stdint.h>

using short8 = __attribute__((ext_vector_type(8))) short;
using us4    = __attribute__((ext_vector_type(4))) unsigned short;
using f32x4  = __attribute__((ext_vector_type(4))) float;
using bf16   = __hip_bfloat16;

constexpr int CB=4, CS=512, CF=16, CD=512, CH=8, CL=6, CDFF=2048, CNC=12, CRPH=64, CDH=64;
constexpr int MROWS = CB*CS;

__device__ inline void gload_lds16(const void* g, void* l) {
    __builtin_amdgcn_global_load_lds((const __attribute__((address_space(1))) void*)g,
                                     (__attribute__((address_space(3))) void*)l, 16, 0, 0);
}
__device__ inline float bfbits2f(unsigned short u) {
    return __uint_as_float(((uint32_t)u) << 16);
}
__device__ inline unsigned short f2bfbits(float f) {
    return __builtin_bit_cast(unsigned short, __float2bfloat16(f));
}

// ---------------------------------------------------------------------------
// GEMM geometry: TPB=256 -> 2x2 wave grid; TPB=512 -> 2x4 wave grid.
template<int BM, int BN, int TPB>
struct MMGeom {
    static constexpr int WC  = (TPB == 512) ? 4 : 2;
    static constexpr int WR  = (TPB/64)/WC;
    static constexpr int RS  = BM/WR;
    static constexpr int CSP = BN/WC;
    static constexpr int MR  = RS/16;
    static constexpr int NR  = CSP/16;
    static constexpr int NLD = (BM+BN)*128/(TPB*16);
};

// BK=64 staging: LDS rows 128 B, XOR swizzle (slot ^= row&7); linear LDS dest +
// inverse-swizzled global source (both-sides rule).
template<int BM, int BN, int TPB>
__device__ inline void stage_tile(const bf16* A, int lda, const bf16* W, int ldw, int k0,
                                  char* As, char* Bs) {
    constexpr int AC = (BM*128)/(TPB*16);
    constexpr int BC = (BN*128)/(TPB*16);
    const int tid = threadIdx.x;
#pragma unroll
    for (int i = 0; i < AC; i++) {
        int s = i*TPB + tid;
        int r = s >> 3, u = s & 7;
        const char* gp = (const char*)(A + (size_t)r*lda + k0) + ((u ^ (r&7))*16);
        gload_lds16(gp, As + (size_t)(s & ~63)*16);
    }
#pragma unroll
    for (int i = 0; i < BC; i++) {
        int s = i*TPB + tid;
        int r = s >> 3, u = s & 7;
        const char* gp = (const char*)(W + (size_t)r*ldw + k0) + ((u ^ (r&7))*16);
        gload_lds16(gp, Bs + (size_t)(s & ~63)*16);
    }
}

template<int BM, int BN, int TPB>
__device__ inline void compute_tile64(const char* As, const char* Bs,
                                      int wr, int wc, int c, int g,
                                      f32x4 (&acc)[MMGeom<BM,BN,TPB>::MR][MMGeom<BM,BN,TPB>::NR]) {
    using G = MMGeom<BM,BN,TPB>;
#pragma unroll
    for (int kk = 0; kk < 2; kk++) {
        short8 af[G::MR], bfv[G::NR];
#pragma unroll
        for (int m = 0; m < G::MR; m++) {
            int row = wr*G::RS + m*16 + c;
            af[m] = *(const short8*)(As + row*128 + (((kk*4+g) ^ (row&7))*16));
        }
#pragma unroll
        for (int n = 0; n < G::NR; n++) {
            int row = wc*G::CSP + n*16 + c;
            bfv[n] = *(const short8*)(Bs + row*128 + (((kk*4+g) ^ (row&7))*16));
        }
#pragma unroll
        for (int m = 0; m < G::MR; m++)
#pragma unroll
            for (int n = 0; n < G::NR; n++)
                acc[m][n] = __builtin_amdgcn_mfma_f32_16x16x32_bf16(af[m], bfv[n], acc[m][n], 0, 0, 0);
    }
}

// 4-buffer ring, ONE barrier per K-step (r9-proven race-free): buffer t&3 is
// rewritten by stage(t+4), issued after barrier(t+1) which all waves pass only
// after finishing compute(t). Counted vmcnt keeps 2 stages in flight.
template<int BM, int BN, int TPB>
__device__ inline void mm_core_pipe(const bf16* A, int lda, const bf16* W, int ldw, int K,
                                    char* smem,
                                    f32x4 (&acc)[MMGeom<BM,BN,TPB>::MR][MMGeom<BM,BN,TPB>::NR]) {
    using G = MMGeom<BM,BN,TPB>;
    constexpr int SSZ = (BM+BN)*128;
    const int tid = threadIdx.x;
    const int lane = tid & 63, wv = tid >> 6;
    const int wr = wv / G::WC, wc = wv % G::WC;
    const int g = lane >> 4, c = lane & 15;

    const int nk = K >> 6;
    stage_tile<BM,BN,TPB>(A, lda, W, ldw, 0, smem, smem + BM*128);
    if (nk > 1) stage_tile<BM,BN,TPB>(A, lda, W, ldw, 64, smem + SSZ, smem + SSZ + BM*128);

    for (int t = 0; t < nk; t++) {
        char* bc = smem + (size_t)(t & 3)*SSZ;
        if (t + 2 < nk) {
            char* bs = smem + (size_t)((t+2) & 3)*SSZ;
            stage_tile<BM,BN,TPB>(A, lda, W, ldw, (t+2)*64, bs, bs + BM*128);
            asm volatile("s_waitcnt vmcnt(%0)" :: "n"(2*G::NLD) : "memory");
        } else if (t + 1 < nk) {
            asm volatile("s_waitcnt vmcnt(%0)" :: "n"(G::NLD) : "memory");
        } else {
            asm volatile("s_waitcnt vmcnt(0)" ::: "memory");
        }
        __builtin_amdgcn_s_barrier();
        compute_tile64<BM,BN,TPB>(bc, bc + BM*128, wr, wc, c, g, acc);
    }
}

// EPI: 0 = bf16+bias ; 1 = bf16+bias+relu ; 2 = f32+bias (bias only on kz==0)
template<int BM, int BN, int EPI, int KSPLIT, int TPB>
__global__ __launch_bounds__(TPB) void k_mm(const bf16* __restrict__ A, int lda,
                                            const bf16* __restrict__ W, int ldw,
                                            const float* __restrict__ bias,
                                            bf16* __restrict__ Cb, float* __restrict__ Cf,
                                            int ldc, int K) {
    using G = MMGeom<BM,BN,TPB>;
    __shared__ char smem[4*(BM+BN)*128];
    const int bm = blockIdx.y * BM, bn = blockIdx.x * BN;
    const int kz = (KSPLIT > 1) ? blockIdx.z : 0;
    const int Kper = K / KSPLIT;
    f32x4 acc[G::MR][G::NR] = {};
    mm_core_pipe<BM,BN,TPB>(A + (size_t)bm*lda + kz*Kper, lda,
                            W + (size_t)bn*ldw + kz*Kper, ldw, Kper, smem, acc);
    const int lane = threadIdx.x & 63, wv = threadIdx.x >> 6;
    const int wr = wv / G::WC, wc = wv % G::WC;
    const int g = lane >> 4, c = lane & 15;
    float* Cfz = Cf + (size_t)kz * MROWS * ldc;
#pragma unroll
    for (int m = 0; m < G::MR; m++)
#pragma unroll
        for (int n = 0; n < G::NR; n++)
#pragma unroll
            for (int j = 0; j < 4; j++) {
                int row = bm + wr*G::RS + m*16 + g*4 + j;
                int col = bn + wc*G::CSP + n*16 + c;
                float v = acc[m][n][j] + ((kz == 0) ? bias[col] : 0.0f);
                if (EPI == 1) v = fmaxf(v, 0.0f);
                if (EPI == 2) Cfz[(size_t)row*ldc + col] = v;
                else          Cb[(size_t)row*ldc + col] = __float2bfloat16(v);
            }
}

// qkv GEMM: writes Q,K into qkvb; V columns written transposed into vtb.
__global__ __launch_bounds__(512) void k_mm_qkv(const bf16* __restrict__ A,
                                                const bf16* __restrict__ W,
                                                const float* __restrict__ bias,
                                                bf16* __restrict__ qkvb,
                                                bf16* __restrict__ vtb) {
    constexpr int BM = 128, BN = 128, TPB = 512;
    using G = MMGeom<BM,BN,TPB>;
    __shared__ char smem[4*(BM+BN)*128];
    const int bm = blockIdx.y * BM, bn = blockIdx.x * BN;
    f32x4 acc[G::MR][G::NR] = {};
    mm_core_pipe<BM,BN,TPB>(A + (size_t)bm*CD, CD, W + (size_t)bn*CD, CD, CD, smem, acc);
    const int lane = threadIdx.x & 63, wv = threadIdx.x >> 6;
    const int wr = wv / G::WC, wc = wv % G::WC;
    const int g = lane >> 4, c = lane & 15;
    if (bn < 2*CD) {
#pragma unroll
        for (int m = 0; m < G::MR; m++)
#pragma unroll
            for (int n = 0; n < G::NR; n++)
#pragma unroll
                for (int j = 0; j < 4; j++) {
                    int row = bm + wr*G::RS + m*16 + g*4 + j;
                    int col = bn + wc*G::CSP + n*16 + c;
                    qkvb[(size_t)row*(3*CD) + col] = __float2bfloat16(acc[m][n][j] + bias[col]);
                }
    } else {
#pragma unroll
        for (int m = 0; m < G::MR; m++)
#pragma unroll
            for (int n = 0; n < G::NR; n++) {
                int row0 = bm + wr*G::RS + m*16 + g*4;
                int col  = bn + wc*G::CSP + n*16 + c;
                int z = (row0 >> 9)*8 + ((col - 2*CD) >> 6);
                int d = (col - 2*CD) & 63;
                int s0 = row0 & 511;
                float bcol = bias[col];
                us4 o;
#pragma unroll
                for (int j = 0; j < 4; j++) o[j] = f2bfbits(acc[m][n][j] + bcol);
                *(us4*)(vtb + ((size_t)z*CDH + d)*CS + s0) = o;
            }
    }
}

// ---------------------------------------------------------------------------
// Fused attention (r9-proven): 4 K/V buffers, one barrier per KV tile, defer-max.
__global__ __launch_bounds__(256) void k_attn_fused(const bf16* __restrict__ qkv,
                                                    const bf16* __restrict__ vt,
                                                    const bf16* __restrict__ bias,
                                                    bf16* __restrict__ att) {
    __shared__ char Ksm[4][16384];
    __shared__ char Vsm[4][16384];
    __shared__ char Ps[16384];

    const int z = blockIdx.y, b = z >> 3, h = z & 7;
    const int qbase = blockIdx.x * 64;
    const int tid = threadIdx.x, l = tid & 63, w = tid >> 6;
    const int g = l >> 4, c = l & 15, swz = l & 7;
    const int q_global = qbase + w*16 + c;

    const bf16* qrow = qkv + ((size_t)(b*CS + q_global))*(3*CD) + h*CDH;
    short8 bq0 = *(const short8*)(qrow + g*8);
    short8 bq1 = *(const short8*)(qrow + 32 + g*8);
    const bf16* brow = bias + ((size_t)z*CS + q_global)*CS;

    float mrun = -1e30f, lsum = 0.0f;
    f32x4 accO[4] = {};
    char* Pb = Ps + w*4096;

    auto stageKV = [&](int kv0, char* Ks, char* Vs) {
#pragma unroll
        for (int i = 0; i < 4; i++) {
            int s = i*256 + tid;
            int r = s >> 3, u = s & 7;
            const bf16* gk = qkv + ((size_t)(b*CS + kv0 + r))*(3*CD) + CD + h*CDH + ((u ^ (r&7)) * 8);
            gload_lds16(gk, Ks + (size_t)(s & ~63)*16);
        }
#pragma unroll
        for (int i = 0; i < 4; i++) {
            int s = i*256 + tid;
            int d = s >> 4, u = s & 15;
            const bf16* gv = vt + ((size_t)(z*CDH + d))*CS + kv0 + ((u ^ (d&7)) * 8);
            gload_lds16(gv, Vs + (size_t)(s & ~63)*16);
        }
    };

    stageKV(0,   Ksm[0], Vsm[0]);
    stageKV(128, Ksm[1], Vsm[1]);

    for (int t = 0; t < 4; t++) {
        int kv0 = t * 128;
        if (t < 2) stageKV((t+2)*128, Ksm[t+2], Vsm[t+2]);
        if (t == 0)      asm volatile("s_waitcnt vmcnt(32)" ::: "memory");
        else if (t == 1) asm volatile("s_waitcnt vmcnt(40)" ::: "memory");
        else if (t == 2) asm volatile("s_waitcnt vmcnt(32)" ::: "memory");
        else             asm volatile("s_waitcnt vmcnt(0)" ::: "memory");
        __builtin_amdgcn_s_barrier();
        const char* Kc = Ksm[t];
        const char* Vc = Vsm[t];

        float sv[8][4];
        float tmax = -1e30f;
#pragma unroll
        for (int n = 0; n < 8; n++) {
            int row = n*16 + c;
            short8 af0 = *(const short8*)(Kc + row*128 + ((g    ^ swz) * 16));
            short8 af1 = *(const short8*)(Kc + row*128 + (((4+g) ^ swz) * 16));
            f32x4 a = {};
            a = __builtin_amdgcn_mfma_f32_16x16x32_bf16(af0, bq0, a, 0, 0, 0);
            a = __builtin_amdgcn_mfma_f32_16x16x32_bf16(af1, bq1, a, 0, 0, 0);
            us4 b4 = *(const us4*)(brow + kv0 + n*16 + g*4);
#pragma unroll
            for (int j = 0; j < 4; j++) {
                sv[n][j] = a[j] * 0.125f + bfbits2f(b4[j]);
                tmax = fmaxf(tmax, sv[n][j]);
            }
        }
        tmax = fmaxf(tmax, __shfl_xor(tmax, 16));
        tmax = fmaxf(tmax, __shfl_xor(tmax, 32));
        if (!__all(tmax - mrun <= 8.0f)) {
            float mnew = fmaxf(mrun, tmax);
            float corr = __expf(mrun - mnew);
            lsum *= corr;
#pragma unroll
            for (int n2 = 0; n2 < 4; n2++)
#pragma unroll
                for (int j = 0; j < 4; j++) accO[n2][j] *= corr;
            mrun = mnew;
        }
        float tsum = 0.0f;
#pragma unroll
        for (int n = 0; n < 8; n++)
#pragma unroll
            for (int j = 0; j < 4; j++) {
                float e = __expf(sv[n][j] - mrun);
                sv[n][j] = e;
                tsum += e;
            }
        tsum += __shfl_xor(tsum, 16);
        tsum += __shfl_xor(tsum, 32);
        lsum += tsum;

#pragma unroll
        for (int n = 0; n < 8; n++) {
            us4 pk;
#pragma unroll
            for (int j = 0; j < 4; j++) pk[j] = f2bfbits(sv[n][j]);
            *(us4*)(Pb + c*256 + ((n*32 + g*8) ^ (swz << 4))) = pk;
        }

#pragma unroll
        for (int n2 = 0; n2 < 4; n2++) {
            int d = n2*16 + c;
#pragma unroll
            for (int kk = 0; kk < 4; kk++) {
                short8 av = *(const short8*)(Vc + d*256 + (((kk*4 + g) ^ swz) * 16));
                short8 bp = *(const short8*)(Pb + c*256 + (((kk*64 + g*16) ^ (swz << 4))));
                accO[n2] = __builtin_amdgcn_mfma_f32_16x16x32_bf16(av, bp, accO[n2], 0, 0, 0);
            }
        }
    }

    float inv = 1.0f / lsum;
    bf16* orow = att + ((size_t)(b*CS + q_global))*CD + h*CDH;
#pragma unroll
    for (int n2 = 0; n2 < 4; n2++) {
        us4 o;
#pragma unroll
        for (int j = 0; j < 4; j++) o[j] = f2bfbits(accO[n2][j] * inv);
        *(us4*)(orow + n2*16 + g*4) = o;
    }
}

// ---------------------------------------------------------------------------
__global__ void k_standardize(const float* __restrict__ x, float* __restrict__ ts,
                              float* __restrict__ fs) {
    int b = blockIdx.x, ch = blockIdx.y, tid = threadIdx.x;
    __shared__ float red[256];
    float v0 = x[(b*CS + tid)*CF + ch];
    float v1 = x[(b*CS + tid + 256)*CF + ch];
    red[tid] = v0 + v1; __syncthreads();
    for (int w = 128; w > 0; w >>= 1) { if (tid < w) red[tid] += red[tid+w]; __syncthreads(); }
    float mean = red[0] * (1.0f/CS); __syncthreads();
    float d0 = v0-mean, d1 = v1-mean;
    red[tid] = d0*d0 + d1*d1; __syncthreads();
    for (int w = 128; w > 0; w >>= 1) { if (tid < w) red[tid] += red[tid+w]; __syncthreads(); }
    float inv = rsqrtf(red[0]*(1.0f/CS) + 1e-6f);
    float* o = ch == 0 ? ts : fs;
    o[b*CS + tid] = d0*inv; o[b*CS + tid + 256] = d1*inv;
}

__global__ __launch_bounds__(256) void k_relpos(const float* __restrict__ ts, const float* __restrict__ fs,
                         const float* __restrict__ w1, const float* __restrict__ b1,
                         const float* __restrict__ w2, const float* __restrict__ b2,
                         bf16* __restrict__ bias) {
    int idx = blockIdx.x * 256 + threadIdx.x;
    int j = idx & (CS-1), i = (idx >> 9) & (CS-1), b = idx >> 18;
    float dt = ts[b*CS + i] - ts[b*CS + j];
    float df = fs[b*CS + i] - fs[b*CS + j];
    float acc[CH];
#pragma unroll
    for (int h = 0; h < CH; h++) acc[h] = b2[h];
    for (int r = 0; r < CRPH; r++) {
        float hd = fmaxf(w1[r*2]*dt + w1[r*2+1]*df + b1[r], 0.0f);
#pragma unroll
        for (int h = 0; h < CH; h++) acc[h] += w2[h*CRPH + r] * hd;
    }
#pragma unroll
    for (int h = 0; h < CH; h++) {
        float v = fminf(fmaxf(acc[h], -5.0f), 5.0f);
        bias[((size_t)(b*CH + h)*CS + i)*CS + j] = __float2bfloat16(v);
    }
}

__global__ __launch_bounds__(256) void k_embed(const float* __restrict__ x, const float* __restrict__ w,
                        const float* __restrict__ bv, float* __restrict__ h, bf16* __restrict__ hb) {
    int idx = blockIdx.x * 256 + threadIdx.x;
    int d = idx & (CD-1), m = idx >> 9;
    const float* xr = x + m*CF;
    const float* wr = w + d*CF;
    float acc = bv[d];
#pragma unroll
    for (int f = 0; f < CF; f++) acc += xr[f]*wr[f];
    h[idx] = acc; hb[idx] = __float2bfloat16(acc);
}

// residual + LN, wave-per-row, vectorized, no LDS. grid = M/4, 256 threads.
template<int NADD>
__global__ __launch_bounds__(256) void k_ln(float* __restrict__ h, const float* __restrict__ a0,
                     const float* __restrict__ a1,
                     const float* __restrict__ s, const float* __restrict__ bv, bf16* __restrict__ hb) {
    const int w = threadIdx.x >> 6, l = threadIdx.x & 63;
    const int row = blockIdx.x*4 + w;
    float* hr = h + (size_t)row*CD;
    const float* ar = a0 + (size_t)row*CD;
    const float* a1r = (NADD == 2) ? (a1 + (size_t)row*CD) : nullptr;

    float v[8];
    {
        float4 h0 = ((const float4*)hr)[l*2],  h1 = ((const float4*)hr)[l*2+1];
        float4 b0 = ((const float4*)ar)[l*2],  b1 = ((const float4*)ar)[l*2+1];
        v[0]=h0.x+b0.x; v[1]=h0.y+b0.y; v[2]=h0.z+b0.z; v[3]=h0.w+b0.w;
        v[4]=h1.x+b1.x; v[5]=h1.y+b1.y; v[6]=h1.z+b1.z; v[7]=h1.w+b1.w;
        if (NADD == 2) {
            float4 c0 = ((const float4*)a1r)[l*2], c1 = ((const float4*)a1r)[l*2+1];
            v[0]+=c0.x; v[1]+=c0.y; v[2]+=c0.z; v[3]+=c0.w;
            v[4]+=c1.x; v[5]+=c1.y; v[6]+=c1.z; v[7]+=c1.w;
        }
    }
    float sum = 0.f, sq = 0.f;
#pragma unroll
    for (int i = 0; i < 8; i++) { sum += v[i]; sq += v[i]*v[i]; }
#pragma unroll
    for (int off = 1; off < 64; off <<= 1) {
        sum += __shfl_xor(sum, off);
        sq  += __shfl_xor(sq, off);
    }
    float mean = sum * (1.0f/CD);
    float var  = sq * (1.0f/CD) - mean*mean;
    float rstd = rsqrtf(var + 1e-5f);

    float4 s0 = ((const float4*)s)[l*2],  s1 = ((const float4*)s)[l*2+1];
    float4 g0 = ((const float4*)bv)[l*2], g1 = ((const float4*)bv)[l*2+1];
    float o[8];
    o[0]=(v[0]-mean)*rstd*s0.x+g0.x; o[1]=(v[1]-mean)*rstd*s0.y+g0.y;
    o[2]=(v[2]-mean)*rstd*s0.z+g0.z; o[3]=(v[3]-mean)*rstd*s0.w+g0.w;
    o[4]=(v[4]-mean)*rstd*s1.x+g1.x; o[5]=(v[5]-mean)*rstd*s1.y+g1.y;
    o[6]=(v[6]-mean)*rstd*s1.z+g1.z; o[7]=(v[7]-mean)*rstd*s1.w+g1.w;

    ((float4*)hr)[l*2]   = make_float4(o[0],o[1],o[2],o[3]);
    ((float4*)hr)[l*2+1] = make_float4(o[4],o[5],o[6],o[7]);
    short8 ob;
#pragma unroll
    for (int i = 0; i < 8; i++) ob[i] = (short)f2bfbits(o[i]);
    *(short8*)(hb + (size_t)row*CD + l*8) = ob;
}

// per-layer fallback weight conversion
__global__ __launch_bounds__(256) void k_wconv(const float* __restrict__ a0, const float* __restrict__ a1,
                        const float* __restrict__ a2, const float* __restrict__ a3,
                        bf16* __restrict__ dst) {
    size_t i = ((size_t)blockIdx.x * 256 + threadIdx.x) * 8;
    const float* src; size_t off;
    if (i < 786432)       { src = a0; off = i; }
    else if (i < 1048576) { src = a1; off = i - 786432; }
    else if (i < 2097152) { src = a2; off = i - 1048576; }
    else                  { src = a3; off = i - 2097152; }
    short8 o;
#pragma unroll
    for (int j = 0; j < 8; j++) o[j] = __builtin_bit_cast(short, __float2bfloat16(src[off + j]));
    *(short8*)(void*)(dst + i) = o;
}

// one-shot conversion of all 6 layers' weights
__global__ __launch_bounds__(256) void k_wconv_all(const float* __restrict__ aiw, const float* __restrict__ aow,
                        const float* __restrict__ f1w, const float* __restrict__ f2w,
                        bf16* __restrict__ dst) {
    int lyr = blockIdx.y;
    size_t i = ((size_t)blockIdx.x * 256 + threadIdx.x) * 8;
    const float* src; size_t off;
    if (i < 786432)       { src = aiw + (size_t)lyr* 786432; off = i; }
    else if (i < 1048576) { src = aow + (size_t)lyr* 262144; off = i - 786432; }
    else if (i < 2097152) { src = f1w + (size_t)lyr*1048576; off = i - 1048576; }
    else                  { src = f2w + (size_t)lyr*1048576; off = i - 2097152; }
    short8 o;
#pragma unroll
    for (int j = 0; j < 8; j++) o[j] = __builtin_bit_cast(short, __float2bfloat16(src[off + j]));
    *(short8*)(void*)(dst + (size_t)lyr*3145728 + i) = o;
}

// pool + fc fused: grid (CB), 256 threads.
__global__ __launch_bounds__(256) void k_poolfc(const float* __restrict__ h,
                                                const float* __restrict__ fcw,
                                                const float* __restrict__ fcb,
                                                float* __restrict__ out) {
    __shared__ float rep[CD];
    int b = blockIdx.x, t = threadIdx.x;
    float a0 = 0.f, a1 = 0.f;
    for (int s = 0; s < CS; s++) {
        const float* row = h + (size_t)(b*CS + s)*CD;
        a0 += row[t];
        a1 += row[t + 256];
    }
    rep[t] = a0 * (1.0f/CS);
    rep[t + 256] = a1 * (1.0f/CS);
    __syncthreads();
    int w = t >> 6, l = t & 63;
    for (int cc = w*3; cc < w*3 + 3 && cc < CNC; cc++) {
        float acc = 0.f;
        for (int d = l; d < CD; d += 64) acc += rep[d] * fcw[cc*CD + d];
        for (int o = 32; o > 0; o >>= 1) acc += __shfl_xor(acc, o);
        if (l == 0) out[b*CNC + cc] = acc + fcb[cc];
    }
}

// ---------------------------------------------------------------------------
extern "C" void kernel_launch(void* const* d_in, const int* in_sizes, int n_in,
                              void* d_out, int out_size, void* d_ws, size_t ws_size,
                              hipStream_t stream) {
    const float* x   = (const float*)d_in[0];
    const float* rw1 = (const float*)d_in[1];
    const float* rb1 = (const float*)d_in[2];
    const float* rw2 = (const float*)d_in[3];
    const float* rb2 = (const float*)d_in[4];
    const float* emw = (const float*)d_in[5];
    const float* emb = (const float*)d_in[6];
    const float* aiw = (const float*)d_in[7];
    const float* aib = (const float*)d_in[8];
    const float* aow = (const float*)d_in[9];
    const float* aob = (const float*)d_in[10];
    const float* f1w = (const float*)d_in[11];
    const float* f1b = (const float*)d_in[12];
    const float* f2w = (const float*)d_in[13];
    const float* f2b = (const float*)d_in[14];
    const float* l1s = (const float*)d_in[15];
    const float* l1b = (const float*)d_in[16];
    const float* l2s = (const float*)d_in[17];
    const float* l2b = (const float*)d_in[18];
    const float* fcw = (const float*)d_in[19];
    const float* fcb = (const float*)d_in[20];
    float* out = (float*)d_out;

    char* p = (char*)d_ws;
    auto alloc = [&](size_t bytes) { char* r = p; p += (bytes + 255) & ~(size_t)255; return r; };
    bf16*  biasb = (bf16*)alloc((size_t)CB*CH*CS*CS*2);    // 16.78 MB
    float* h     = (float*)alloc((size_t)MROWS*CD*4);      // 4.19 MB
    bf16*  hb    = (bf16*)alloc((size_t)MROWS*CD*2);       // 2.10 MB
    bf16*  qkvb  = (bf16*)alloc((size_t)MROWS*3*CD*2);     // 6.29 MB
    bf16*  vtb   = (bf16*)alloc((size_t)CB*CH*CDH*CS*2);   // 2.10 MB
    bf16*  attb  = (bf16*)alloc((size_t)MROWS*CD*2);       // 2.10 MB
    float* tmp   = (float*)alloc((size_t)2*MROWS*CD*4);    // 8.39 MB (2 split-K slabs)
    bf16*  ffb   = (bf16*)alloc((size_t)MROWS*CDFF*2);     // 8.39 MB
    bf16*  wl    = (bf16*)alloc((size_t)3145728*2);        // 6.29 MB (fallback)
    float* ts    = (float*)alloc(CB*CS*4);
    float* fs    = (float*)alloc(CB*CS*4);

    size_t used = (size_t)(p - (char*)d_ws);
    const size_t WLE = 3145728;
    bool oneshot = (ws_size > used) && ((ws_size - used) >= (size_t)CL*WLE*2 + 256);
    bf16* wlall = (bf16*)alloc(oneshot ? (size_t)CL*WLE*2 : 0);

    const int M = MROWS;
    float* tmp2 = tmp + (size_t)M*CD;

    k_standardize<<<dim3(CB,2), 256, 0, stream>>>(x, ts, fs);
    k_relpos<<<(CB*CS*CS)/256, 256, 0, stream>>>(ts, fs, rw1, rb1, rw2, rb2, biasb);
    k_embed<<<(M*CD)/256, 256, 0, stream>>>(x, emw, emb, h, hb);
    if (oneshot)
        k_wconv_all<<<dim3(1536, CL), 256, 0, stream>>>(aiw, aow, f1w, f2w, wlall);

    for (int l = 0; l < CL; l++) {
        const bf16* wbase = oneshot ? (wlall + (size_t)l*WLE) : wl;
        if (!oneshot)
            k_wconv<<<1536, 256, 0, stream>>>(aiw + (size_t)l*786432, aow + (size_t)l*262144,
                                              f1w + (size_t)l*1048576, f2w + (size_t)l*1048576, wl);
        const bf16* wl_aiw = wbase;
        const bf16* wl_aow = wbase + 786432;
        const bf16* wl_f1w = wbase + 1048576;
        const bf16* wl_f2w = wbase + 2097152;
        // qkv = h @ aiw^T + aib ; V part written transposed into vtb
        k_mm_qkv<<<dim3(12,16), 512, 0, stream>>>(hb, wl_aiw, aib + (size_t)l*3*CD, qkvb, vtb);
        // fused attention
        k_attn_fused<<<dim3(CS/64, CB*CH), 256, 0, stream>>>(qkvb, vtb, biasb, attb);
        // out projection -> tmp (f32)
        k_mm<64,64,2,1,512><<<dim3(8,32), 512, 0, stream>>>(attb, CD, wl_aow, CD,
                                                            aob + (size_t)l*CD, nullptr, tmp, CD, CD);
        k_ln<1><<<M/4, 256, 0, stream>>>(h, tmp, nullptr, l1s + (size_t)l*CD, l1b + (size_t)l*CD, hb);
        // ff1 (relu)
        k_mm<128,128,1,1,512><<<dim3(16,16), 512, 0, stream>>>(hb, CD, wl_f1w, CD,
                                                               f1b + (size_t)l*CDFF, ffb, nullptr, CDFF, CD);
        // ff2 -> split-K=2 slabs tmp/tmp2 (f32)
        k_mm<64,64,2,2,512><<<dim3(8,32,2), 512, 0, stream>>>(ffb, CDFF, wl_f2w, CDFF,
                                                              f2b + (size_t)l*CD, nullptr, tmp, CD, CDFF);
        k_ln<2><<<M/4, 256, 0, stream>>>(h, tmp, tmp2, l2s + (size_t)l*CD, l2b + (size_t)l*CD, hb);
    }

    k_poolfc<<<CB, 256, 0, stream>>>(h, fcw, fcb, out);
}